// Round 15
// baseline (311.464 us; speedup 1.0000x reference)
//
#include <hip/hip_runtime.h>
#include <hip/hip_bf16.h>

#define B_ 8
#define C_ 64
#define N_ 4096
#define K_ 20
#define EPS_ 1e-5f
#define SLOPE_ 0.2f

typedef __attribute__((ext_vector_type(8))) short bf16x8;
typedef __attribute__((ext_vector_type(4))) float f32x4;

__device__ __forceinline__ float lrelu(float x) { return x >= 0.f ? x : SLOPE_ * x; }
__device__ __forceinline__ float bf2f(unsigned short u) {
    return __uint_as_float(((unsigned int)u) << 16);
}
__device__ __forceinline__ unsigned short f2bf(float f) {
    unsigned int u = __float_as_uint(f);
    return (unsigned short)((u + 0x7FFFu + ((u >> 16) & 1u)) >> 16);
}

__device__ __forceinline__ float rdlanef(float x, int l) {
    return __int_as_float(__builtin_amdgcn_readlane(__float_as_int(x), l));
}

// split 8 floats into hi/lo bf16x8
__device__ __forceinline__ void split8(const float* v, bf16x8& h, bf16x8& l) {
#pragma unroll
    for (int j = 0; j < 8; ++j) {
        unsigned short hh = f2bf(v[j]);
        h[j] = (short)hh;
        l[j] = (short)f2bf(v[j] - bf2f(hh));
    }
}

// ---------------------------------------------------------------------------
// Kernel A (MFMA): Y[128x64] = [wA;wB] @ xs via split-bf16 MFMA.
// yA = rows 0..63; dd = rows 64..127 - rows 0..63. Also xx and xps images.
// grid 512 (B * N/64), block 256
// ---------------------------------------------------------------------------
__global__ void __launch_bounds__(256) k_pre(const float* __restrict__ x,
                                             const float* __restrict__ wk1,
                                             float* __restrict__ yA,
                                             float* __restrict__ dd,
                                             float* __restrict__ xx,
                                             unsigned short* __restrict__ xps) {
    __shared__ float xs[64][64];
    __shared__ unsigned short wimg[16384];
    __shared__ unsigned short ximg[8192];
    int t = threadIdx.x;
    int lane = t & 63;
    int w = t >> 6;
    int blk = blockIdx.x;
    int b = blk >> 6;
    int n0 = (blk & 63) << 6;

    const float* xb = x + (size_t)b * C_ * N_;
    for (int i = 0; i < 4; ++i) {
        int j = i * 256 + t;
        int c = j >> 4;
        int p4 = (j & 15) << 2;
        float4 v = *(const float4*)(xb + c * N_ + n0 + p4);
        xs[c][p4 + 0] = v.x; xs[c][p4 + 1] = v.y;
        xs[c][p4 + 2] = v.z; xs[c][p4 + 3] = v.w;
    }
    for (int rep = 0; rep < 4; ++rep) {
        int i = rep * 256 + t;
        int m = i >> 3, oct = i & 7;
        const float* src = wk1 + (m & 63) * 128 + ((m >> 6) << 6) + oct * 8;
        float4 a4 = *(const float4*)src;
        float4 b4 = *(const float4*)(src + 4);
        float wv[8] = {a4.x, a4.y, a4.z, a4.w, b4.x, b4.y, b4.z, b4.w};
        bf16x8 hv, lv8;
        split8(wv, hv, lv8);
        int unit = oct ^ (m & 7);
        *(bf16x8*)&wimg[m * 64 + unit * 8] = hv;
        *(bf16x8*)&wimg[8192 + m * 64 + unit * 8] = lv8;
    }
    __syncthreads();

    if (t < 64) {
        float s = 0.f;
        for (int c = 0; c < 64; ++c) { float xv = xs[c][t]; s += xv * xv; }
        xx[b * N_ + n0 + t] = s;
    }

    unsigned short* xc = xps + ((size_t)(b * 64 + (blk & 63))) * 8192;
#pragma unroll
    for (int q = 0; q < 2; ++q) {
        int i = q * 256 + t;
        int nl = i >> 3, oct = i & 7;
        float wv[8];
#pragma unroll
        for (int j = 0; j < 8; ++j) wv[j] = xs[oct * 8 + j][nl];
        bf16x8 hv, lv8;
        split8(wv, hv, lv8);
        int unit = oct ^ (nl & 7);
        *(bf16x8*)&ximg[nl * 64 + unit * 8] = hv;
        *(bf16x8*)&ximg[4096 + nl * 64 + unit * 8] = lv8;
        *(bf16x8*)&xc[nl * 64 + unit * 8] = hv;
        *(bf16x8*)&xc[4096 + nl * 64 + unit * 8] = lv8;
    }
    __syncthreads();

    int mA = (w << 4) + (lane & 15);
    int mB = ((w + 4) << 4) + (lane & 15);
    bf16x8 ahA[2], alA[2], ahB[2], alB[2];
#pragma unroll
    for (int kc = 0; kc < 2; ++kc) {
        int uA = (kc * 4 + (lane >> 4)) ^ (mA & 7);
        int uB = (kc * 4 + (lane >> 4)) ^ (mB & 7);
        ahA[kc] = *(const bf16x8*)&wimg[mA * 64 + uA * 8];
        alA[kc] = *(const bf16x8*)&wimg[8192 + mA * 64 + uA * 8];
        ahB[kc] = *(const bf16x8*)&wimg[mB * 64 + uB * 8];
        alB[kc] = *(const bf16x8*)&wimg[8192 + mB * 64 + uB * 8];
    }
    size_t pbase = (size_t)(b * N_ + n0);
#pragma unroll
    for (int nt = 0; nt < 4; ++nt) {
        int p = nt * 16 + (lane & 15);
        int u0 = ((lane >> 4)) ^ (p & 7);
        int u1 = (4 + (lane >> 4)) ^ (p & 7);
        bf16x8 bh0 = *(const bf16x8*)&ximg[p * 64 + u0 * 8];
        bf16x8 bl0 = *(const bf16x8*)&ximg[4096 + p * 64 + u0 * 8];
        bf16x8 bh1 = *(const bf16x8*)&ximg[p * 64 + u1 * 8];
        bf16x8 bl1 = *(const bf16x8*)&ximg[4096 + p * 64 + u1 * 8];
        f32x4 aA = {0.f, 0.f, 0.f, 0.f};
        aA = __builtin_amdgcn_mfma_f32_16x16x32_bf16(ahA[0], bh0, aA, 0, 0, 0);
        aA = __builtin_amdgcn_mfma_f32_16x16x32_bf16(ahA[0], bl0, aA, 0, 0, 0);
        aA = __builtin_amdgcn_mfma_f32_16x16x32_bf16(alA[0], bh0, aA, 0, 0, 0);
        aA = __builtin_amdgcn_mfma_f32_16x16x32_bf16(alA[0], bl0, aA, 0, 0, 0);
        aA = __builtin_amdgcn_mfma_f32_16x16x32_bf16(ahA[1], bh1, aA, 0, 0, 0);
        aA = __builtin_amdgcn_mfma_f32_16x16x32_bf16(ahA[1], bl1, aA, 0, 0, 0);
        aA = __builtin_amdgcn_mfma_f32_16x16x32_bf16(alA[1], bh1, aA, 0, 0, 0);
        aA = __builtin_amdgcn_mfma_f32_16x16x32_bf16(alA[1], bl1, aA, 0, 0, 0);
        f32x4 aB = {0.f, 0.f, 0.f, 0.f};
        aB = __builtin_amdgcn_mfma_f32_16x16x32_bf16(ahB[0], bh0, aB, 0, 0, 0);
        aB = __builtin_amdgcn_mfma_f32_16x16x32_bf16(ahB[0], bl0, aB, 0, 0, 0);
        aB = __builtin_amdgcn_mfma_f32_16x16x32_bf16(alB[0], bh0, aB, 0, 0, 0);
        aB = __builtin_amdgcn_mfma_f32_16x16x32_bf16(alB[0], bl0, aB, 0, 0, 0);
        aB = __builtin_amdgcn_mfma_f32_16x16x32_bf16(ahB[1], bh1, aB, 0, 0, 0);
        aB = __builtin_amdgcn_mfma_f32_16x16x32_bf16(ahB[1], bl1, aB, 0, 0, 0);
        aB = __builtin_amdgcn_mfma_f32_16x16x32_bf16(alB[1], bh1, aB, 0, 0, 0);
        aB = __builtin_amdgcn_mfma_f32_16x16x32_bf16(alB[1], bl1, aB, 0, 0, 0);

        int obase = (w << 4) + ((lane >> 4) << 2);
        float4 ya4 = {aA[0], aA[1], aA[2], aA[3]};
        float4 dd4 = {aB[0] - aA[0], aB[1] - aA[1], aB[2] - aA[2], aB[3] - aA[3]};
        *(float4*)(yA + (pbase + p) * 64 + obase) = ya4;
        *(float4*)(dd + (pbase + p) * 64 + obase) = dd4;
    }
}

// ---------------------------------------------------------------------------
// Kernel B: top-20 neighbors. Round-14 structure, with the 4 per-row insert
// loops FUSED into one interleaved loop (4 independent chains overlap).
// Per-row candidate processing order is bit-identical.
// ---------------------------------------------------------------------------
__global__ void __launch_bounds__(512) k_topk(const unsigned short* __restrict__ xps,
                                              const float* __restrict__ xx,
                                              int* __restrict__ idxg) {
    __shared__ float sc[2][32][68];
    int t = threadIdx.x;
    int lane = t & 63;
    int w = t >> 6;
    int wr = w >> 2;
    int wc = w & 3;
    int blk = blockIdx.x;
    int b = blk >> 7;
    int n0 = (blk & 127) << 5;
    int bc = b << 6;
    const float* xxb = xx + b * N_;
    int pa = ((lane + 1) & 63) << 2;

    const unsigned short* xcA = xps + ((size_t)(bc + ((blk & 127) >> 1))) * 8192;
    int anl = ((blk & 1) << 5) + (wr << 4) + (lane & 15);
    bf16x8 ah[2], al[2];
#pragma unroll
    for (int kc = 0; kc < 2; ++kc) {
        int unit = (kc * 4 + (lane >> 4)) ^ (anl & 7);
        ah[kc] = *(const bf16x8*)&xcA[anl * 64 + unit * 8];
        al[kc] = *(const bf16x8*)&xcA[4096 + anl * 64 + unit * 8];
    }

    int n_ = (wc << 4) + (lane & 15);
    int off0 = n_ * 64 + (((lane >> 4)) ^ (n_ & 7)) * 8;
    int off1 = n_ * 64 + ((4 + (lane >> 4)) ^ (n_ & 7)) * 8;

    float lv[4];
    int   li[4];
#pragma unroll
    for (int i = 0; i < 4; ++i) { lv[i] = -3.0e38f; li[i] = 0; }

    // one insert-step for row r: consume lowest bit of mask, sorted-insert.
    auto step = [&](float& lvr, int& lir, float s,
                    unsigned long long& mask, int m0) {
        int j = (int)__builtin_ctzll(mask);
        mask &= mask - 1;
        float sv = rdlanef(s, j);
        unsigned long long gt = __ballot(lane < 20 && lvr > sv);
        int cpos = __popcll(gt);
        float upv = __int_as_float(
            __builtin_amdgcn_ds_permute(pa, __float_as_int(lvr)));
        int   upi = __builtin_amdgcn_ds_permute(pa, lir);
        if (lane >= cpos && lane < 20) {
            lvr = (lane == cpos) ? sv : upv;
            lir = (lane == cpos) ? (m0 + j) : upi;
        }
    };

    // fused 4-row selection: chains for the 4 rows interleave (ILP).
    auto sel4 = [&](int buf, int m0) {
        int rbase = w << 2;
        float s0 = sc[buf][rbase + 0][lane];
        float s1 = sc[buf][rbase + 1][lane];
        float s2 = sc[buf][rbase + 2][lane];
        float s3 = sc[buf][rbase + 3][lane];
        unsigned long long k0 = __ballot(s0 > rdlanef(lv[0], 19));
        unsigned long long k1 = __ballot(s1 > rdlanef(lv[1], 19));
        unsigned long long k2 = __ballot(s2 > rdlanef(lv[2], 19));
        unsigned long long k3 = __ballot(s3 > rdlanef(lv[3], 19));
        while (k0 | k1 | k2 | k3) {
            if (k0) step(lv[0], li[0], s0, k0, m0);
            if (k1) step(lv[1], li[1], s1, k1, m0);
            if (k2) step(lv[2], li[2], s2, k2, m0);
            if (k3) step(lv[3], li[3], s3, k3, m0);
        }
    };

    const unsigned short* xcB = xps + (size_t)bc * 8192;
    bf16x8 bh0 = *(const bf16x8*)&xcB[off0];
    bf16x8 bl0 = *(const bf16x8*)&xcB[4096 + off0];
    bf16x8 bh1 = *(const bf16x8*)&xcB[off1];
    bf16x8 bl1 = *(const bf16x8*)&xcB[4096 + off1];
    float xxv = xxb[n_];

    for (int mc = 0; mc < 64; ++mc) {
        f32x4 acc = {0.f, 0.f, 0.f, 0.f};
        acc = __builtin_amdgcn_mfma_f32_16x16x32_bf16(ah[0], bh0, acc, 0, 0, 0);
        acc = __builtin_amdgcn_mfma_f32_16x16x32_bf16(ah[0], bl0, acc, 0, 0, 0);
        acc = __builtin_amdgcn_mfma_f32_16x16x32_bf16(al[0], bh0, acc, 0, 0, 0);
        acc = __builtin_amdgcn_mfma_f32_16x16x32_bf16(al[0], bl0, acc, 0, 0, 0);
        acc = __builtin_amdgcn_mfma_f32_16x16x32_bf16(ah[1], bh1, acc, 0, 0, 0);
        acc = __builtin_amdgcn_mfma_f32_16x16x32_bf16(ah[1], bl1, acc, 0, 0, 0);
        acc = __builtin_amdgcn_mfma_f32_16x16x32_bf16(al[1], bh1, acc, 0, 0, 0);
        acc = __builtin_amdgcn_mfma_f32_16x16x32_bf16(al[1], bl1, acc, 0, 0, 0);

#pragma unroll
        for (int r = 0; r < 4; ++r)
            sc[mc & 1][(wr << 4) + ((lane >> 4) << 2) + r][n_] = 2.f * acc[r] - xxv;

        if (mc + 1 < 64) {
            const unsigned short* xn2 = xps + (size_t)(bc + mc + 1) * 8192;
            bh0 = *(const bf16x8*)&xn2[off0];
            bl0 = *(const bf16x8*)&xn2[4096 + off0];
            bh1 = *(const bf16x8*)&xn2[off1];
            bl1 = *(const bf16x8*)&xn2[4096 + off1];
            xxv = xxb[((mc + 1) << 6) + n_];
        }

        if (mc > 0) sel4((mc - 1) & 1, (mc - 1) << 6);
        __syncthreads();
    }

    sel4(1, 63 << 6);

#pragma unroll
    for (int i = 0; i < 4; ++i) {
        int n = n0 + (w << 2) + i;
        if (lane < K_)
            idxg[((size_t)(b * N_ + n)) * K_ + lane] = li[i];
    }
}

// ---------------------------------------------------------------------------
// Kernel C1 (MFMA): gather+BN1 -> split-bf16 images -> MFMA GEMM
// (unchanged — proven)
// ---------------------------------------------------------------------------
__global__ void __launch_bounds__(256) k_edge(const float* __restrict__ yA,
                                              const float* __restrict__ dd,
                                              const int* __restrict__ idxg,
                                              const float* __restrict__ wk2,
                                              const float* __restrict__ g1,
                                              const float* __restrict__ bb1,
                                              const float* __restrict__ mm1,
                                              const float* __restrict__ vv1,
                                              const float* __restrict__ g2,
                                              const float* __restrict__ bb2,
                                              const float* __restrict__ mm2,
                                              const float* __restrict__ vv2,
                                              float* __restrict__ ht) {
    __shared__ unsigned short wimg[8192];
    __shared__ float ubuf[64 * 164];
    __shared__ float s1c[64], t1c[64], s2c[64], t2c[64];
    __shared__ float ddl[8][64];
    __shared__ int   il[8][K_];
    __shared__ float hl[8][64];
    unsigned short* timgH = (unsigned short*)ubuf;
    unsigned short* timgL = timgH + 160 * 64;
    float* ct = ubuf;

    int t = threadIdx.x;
    int lane = t & 63;
    int w = t >> 6;
    int blk = blockIdx.x;
    int b = blk >> 9;
    int n0 = (blk & 511) << 3;

    for (int rep = 0; rep < 2; ++rep) {
        int i = rep * 256 + t;
        int row = i >> 3, oct = i & 7;
        float4 wa = *(const float4*)(wk2 + row * 64 + oct * 8);
        float4 wb = *(const float4*)(wk2 + row * 64 + oct * 8 + 4);
        float wv[8] = {wa.x, wa.y, wa.z, wa.w, wb.x, wb.y, wb.z, wb.w};
        bf16x8 hv, lv8;
        split8(wv, hv, lv8);
        int unit = oct ^ (row & 7);
        *(bf16x8*)&wimg[row * 64 + unit * 8] = hv;
        *(bf16x8*)&wimg[4096 + row * 64 + unit * 8] = lv8;
    }
    if (t < 64) {
        float g = g1[t], be = bb1[t], m = mm1[t], v = vv1[t];
        float s = g * rsqrtf(v + EPS_);
        s1c[t] = s; t1c[t] = be - m * s;
        g = g2[t]; be = bb2[t]; m = mm2[t]; v = vv2[t];
        s = g * rsqrtf(v + EPS_);
        s2c[t] = s; t2c[t] = be - m * s;
    }
    size_t pbase = (size_t)(b * N_ + n0);
    for (int i = t; i < 512; i += 256) {
        int pt = i >> 6, o = i & 63;
        ddl[pt][o] = dd[(pbase + pt) * 64 + o];
    }
    if (t < 8 * K_) {
        int pt = t / K_, k = t % K_;
        il[pt][k] = idxg[(pbase + pt) * K_ + k];
    }
    __syncthreads();

    const float* yAb = yA + (size_t)(b * N_) * 64;
    float4 ga[5][2];
    int gcol[5], goct[5], gpt[5];
#pragma unroll
    for (int rep = 0; rep < 5; ++rep) {
        int j = rep * 256 + t;
        int pt = j / 160;
        int r = j - pt * 160;
        int k = r >> 3, oct = r & 7;
        int m = il[pt][k];
        const float* src = yAb + (size_t)m * 64 + oct * 8;
        ga[rep][0] = *(const float4*)src;
        ga[rep][1] = *(const float4*)(src + 4);
        gcol[rep] = pt * 20 + k; goct[rep] = oct; gpt[rep] = pt;
    }
#pragma unroll
    for (int rep = 0; rep < 5; ++rep) {
        int oct = goct[rep], pt = gpt[rep], col = gcol[rep];
        float yv[8] = {ga[rep][0].x, ga[rep][0].y, ga[rep][0].z, ga[rep][0].w,
                       ga[rep][1].x, ga[rep][1].y, ga[rep][1].z, ga[rep][1].w};
        float tv[8];
#pragma unroll
        for (int jj = 0; jj < 8; ++jj) {
            int oc = oct * 8 + jj;
            tv[jj] = lrelu(s1c[oc] * (yv[jj] + ddl[pt][oc]) + t1c[oc]);
        }
        bf16x8 hv, lv8;
        split8(tv, hv, lv8);
        int unit = oct ^ (col & 7);
        *(bf16x8*)&timgH[col * 64 + unit * 8] = hv;
        *(bf16x8*)&timgL[col * 64 + unit * 8] = lv8;
    }
    __syncthreads();

    int anl = (w << 4) + (lane & 15);
    bf16x8 ah[2], al[2];
#pragma unroll
    for (int kc = 0; kc < 2; ++kc) {
        int unit = (kc * 4 + (lane >> 4)) ^ (anl & 7);
        ah[kc] = *(const bf16x8*)&wimg[anl * 64 + unit * 8];
        al[kc] = *(const bf16x8*)&wimg[4096 + anl * 64 + unit * 8];
    }
    f32x4 acc[10];
#pragma unroll
    for (int nt = 0; nt < 10; ++nt) {
        int col = nt * 16 + (lane & 15);
        int u0 = ((lane >> 4)) ^ (col & 7);
        int u1 = (4 + (lane >> 4)) ^ (col & 7);
        bf16x8 bh0 = *(const bf16x8*)&timgH[col * 64 + u0 * 8];
        bf16x8 bl0 = *(const bf16x8*)&timgL[col * 64 + u0 * 8];
        bf16x8 bh1 = *(const bf16x8*)&timgH[col * 64 + u1 * 8];
        bf16x8 bl1 = *(const bf16x8*)&timgL[col * 64 + u1 * 8];
        f32x4 a = {0.f, 0.f, 0.f, 0.f};
        a = __builtin_amdgcn_mfma_f32_16x16x32_bf16(ah[0], bh0, a, 0, 0, 0);
        a = __builtin_amdgcn_mfma_f32_16x16x32_bf16(ah[0], bl0, a, 0, 0, 0);
        a = __builtin_amdgcn_mfma_f32_16x16x32_bf16(al[0], bh0, a, 0, 0, 0);
        a = __builtin_amdgcn_mfma_f32_16x16x32_bf16(al[0], bl0, a, 0, 0, 0);
        a = __builtin_amdgcn_mfma_f32_16x16x32_bf16(ah[1], bh1, a, 0, 0, 0);
        a = __builtin_amdgcn_mfma_f32_16x16x32_bf16(ah[1], bl1, a, 0, 0, 0);
        a = __builtin_amdgcn_mfma_f32_16x16x32_bf16(al[1], bh1, a, 0, 0, 0);
        a = __builtin_amdgcn_mfma_f32_16x16x32_bf16(al[1], bl1, a, 0, 0, 0);
        acc[nt] = a;
    }
    __syncthreads();

#pragma unroll
    for (int nt = 0; nt < 10; ++nt) {
#pragma unroll
        for (int r = 0; r < 4; ++r)
            ct[((w << 4) + ((lane >> 4) << 2) + r) * 164 + nt * 16 + (lane & 15)] =
                acc[nt][r];
    }
    __syncthreads();

#pragma unroll
    for (int rep = 0; rep < 2; ++rep) {
        int pair = rep * 256 + t;
        int o2 = pair >> 3, pt = pair & 7;
        const float* row = &ct[o2 * 164 + pt * 20];
        float4 c0 = *(const float4*)(row + 0);
        float4 c1 = *(const float4*)(row + 4);
        float4 c2 = *(const float4*)(row + 8);
        float4 c3 = *(const float4*)(row + 12);
        float4 c4 = *(const float4*)(row + 16);
        float mx = fmaxf(fmaxf(fmaxf(c0.x, c0.y), fmaxf(c0.z, c0.w)),
                   fmaxf(fmaxf(fmaxf(c1.x, c1.y), fmaxf(c1.z, c1.w)),
                   fmaxf(fmaxf(fmaxf(c2.x, c2.y), fmaxf(c2.z, c2.w)),
                   fmaxf(fmaxf(fmaxf(c3.x, c3.y), fmaxf(c3.z, c3.w)),
                         fmaxf(fmaxf(c4.x, c4.y), fmaxf(c4.z, c4.w))))));
        hl[pt][o2] = lrelu(s2c[o2] * mx + t2c[o2]);
    }
    __syncthreads();

    float* htb = ht + (size_t)b * 64 * N_;
    for (int i = t; i < 512; i += 256) {
        int o = i >> 3, pt2 = i & 7;
        htb[o * N_ + n0 + pt2] = hl[pt2][o];
    }
}

// ---------------------------------------------------------------------------
// Kernel C2 (MFMA): head 64 -> 256 -> 128 -> 1 (unchanged — proven)
// ---------------------------------------------------------------------------
__global__ void __launch_bounds__(256) k_head(const float* __restrict__ ht,
                                              const float* __restrict__ w1,
                                              const float* __restrict__ g1,
                                              const float* __restrict__ bb1,
                                              const float* __restrict__ mm1,
                                              const float* __restrict__ vv1,
                                              const float* __restrict__ w2,
                                              const float* __restrict__ g2,
                                              const float* __restrict__ bb2,
                                              const float* __restrict__ mm2,
                                              const float* __restrict__ vv2,
                                              const float* __restrict__ w3,
                                              const float* __restrict__ b3,
                                              float* __restrict__ out) {
    __shared__ unsigned int himgH[64 * 36];
    __shared__ unsigned int himgL[64 * 36];
    __shared__ float a1f[64 * 132];
    __shared__ float sA[256], tA[256], sB[128], tB[128], w3s[128];
    __shared__ float outp[4][64];
    int t = threadIdx.x;
    int lane = t & 63;
    int w = t >> 6;
    int blk = blockIdx.x;
    int b = blk >> 6;
    int n0 = (blk & 63) << 6;
    const float* htb = ht + (size_t)b * 64 * N_;

#pragma unroll
    for (int rep = 0; rep < 8; ++rep) {
        int i = rep * 256 + t;
        int pt = i & 63, op = i >> 6;
        float v0 = htb[(2 * op) * N_ + n0 + pt];
        float v1 = htb[(2 * op + 1) * N_ + n0 + pt];
        unsigned short h0 = f2bf(v0), h1 = f2bf(v1);
        unsigned short l0 = f2bf(v0 - bf2f(h0)), l1 = f2bf(v1 - bf2f(h1));
        himgH[pt * 36 + op] = (unsigned int)h0 | ((unsigned int)h1 << 16);
        himgL[pt * 36 + op] = (unsigned int)l0 | ((unsigned int)l1 << 16);
    }
    {
        float g = g1[t], be = bb1[t], m = mm1[t], v = vv1[t];
        float s = g * rsqrtf(v + EPS_);
        sA[t] = s; tA[t] = be - m * s;
    }
    if (t < 128) {
        float g = g2[t], be = bb2[t], m = mm2[t], v = vv2[t];
        float s = g * rsqrtf(v + EPS_);
        sB[t] = s; tB[t] = be - m * s;
        w3s[t] = w3[t];
    }
    __syncthreads();

    f32x4 acc2[2][4];
#pragma unroll
    for (int i = 0; i < 2; ++i)
#pragma unroll
        for (int j = 0; j < 4; ++j) acc2[i][j] = (f32x4){0.f, 0.f, 0.f, 0.f};

    for (int ka = 0; ka < 2; ++ka) {
        bf16x8 wh[2][2], wl[2][2];
#pragma unroll
        for (int mtl2 = 0; mtl2 < 2; ++mtl2) {
            int mabs = 128 * ka + ((2 * w + mtl2) << 4) + (lane & 15);
#pragma unroll
            for (int kc = 0; kc < 2; ++kc) {
                const float* p = w1 + mabs * 64 + kc * 32 + ((lane >> 4) << 3);
                float4 q0 = *(const float4*)p;
                float4 q1 = *(const float4*)(p + 4);
                float vv8[8] = {q0.x, q0.y, q0.z, q0.w, q1.x, q1.y, q1.z, q1.w};
                split8(vv8, wh[mtl2][kc], wl[mtl2][kc]);
            }
        }
#pragma unroll
        for (int nt = 0; nt < 4; ++nt) {
            int pt = (nt << 4) + (lane & 15);
            f32x4 aAcc[2] = {{0.f, 0.f, 0.f, 0.f}, {0.f, 0.f, 0.f, 0.f}};
#pragma unroll
            for (int kc = 0; kc < 2; ++kc) {
                int chb = kc * 32 + ((lane >> 4) << 3);
                bf16x8 bh = *(const bf16x8*)((const unsigned short*)himgH + pt * 72 + chb);
                bf16x8 bl = *(const bf16x8*)((const unsigned short*)himgL + pt * 72 + chb);
#pragma unroll
                for (int mtl2 = 0; mtl2 < 2; ++mtl2) {
                    aAcc[mtl2] = __builtin_amdgcn_mfma_f32_16x16x32_bf16(wh[mtl2][kc], bh, aAcc[mtl2], 0, 0, 0);
                    aAcc[mtl2] = __builtin_amdgcn_mfma_f32_16x16x32_bf16(wh[mtl2][kc], bl, aAcc[mtl2], 0, 0, 0);
                    aAcc[mtl2] = __builtin_amdgcn_mfma_f32_16x16x32_bf16(wl[mtl2][kc], bh, aAcc[mtl2], 0, 0, 0);
                    aAcc[mtl2] = __builtin_amdgcn_mfma_f32_16x16x32_bf16(wl[mtl2][kc], bl, aAcc[mtl2], 0, 0, 0);
                }
            }
#pragma unroll
            for (int mtl2 = 0; mtl2 < 2; ++mtl2) {
                int klocal = ((2 * w + mtl2) << 4) + ((lane >> 4) << 2);
                int rabs = 128 * ka + klocal;
                float4 ov;
                ov.x = lrelu(sA[rabs + 0] * aAcc[mtl2][0] + tA[rabs + 0]);
                ov.y = lrelu(sA[rabs + 1] * aAcc[mtl2][1] + tA[rabs + 1]);
                ov.z = lrelu(sA[rabs + 2] * aAcc[mtl2][2] + tA[rabs + 2]);
                ov.w = lrelu(sA[rabs + 3] * aAcc[mtl2][3] + tA[rabs + 3]);
                *(float4*)&a1f[pt * 132 + klocal] = ov;
            }
        }
        __syncthreads();

#pragma unroll
        for (int kc2 = 0; kc2 < 4; ++kc2) {
            bf16x8 ah2[2], al2[2];
#pragma unroll
            for (int mt2 = 0; mt2 < 2; ++mt2) {
                int oabs = (w << 5) + (mt2 << 4) + (lane & 15);
                const float* p = w2 + oabs * 256 + 128 * ka + kc2 * 32 + ((lane >> 4) << 3);
                float4 q0 = *(const float4*)p;
                float4 q1 = *(const float4*)(p + 4);
                float vv8[8] = {q0.x, q0.y, q0.z, q0.w, q1.x, q1.y, q1.z, q1.w};
                split8(vv8, ah2[mt2], al2[mt2]);
            }
#pragma unroll
            for (int nt = 0; nt < 4; ++nt) {
                int pt = (nt << 4) + (lane & 15);
                int kl = kc2 * 32 + ((lane >> 4) << 3);
                float4 q0 = *(const float4*)&a1f[pt * 132 + kl];
                float4 q1 = *(const float4*)&a1f[pt * 132 + kl + 4];
                float vv8[8] = {q0.x, q0.y, q0.z, q0.w, q1.x, q1.y, q1.z, q1.w};
                bf16x8 bh, bl;
                split8(vv8, bh, bl);
#pragma unroll
                for (int mt2 = 0; mt2 < 2; ++mt2) {
                    acc2[mt2][nt] = __builtin_amdgcn_mfma_f32_16x16x32_bf16(ah2[mt2], bh, acc2[mt2][nt], 0, 0, 0);
                    acc2[mt2][nt] = __builtin_amdgcn_mfma_f32_16x16x32_bf16(ah2[mt2], bl, acc2[mt2][nt], 0, 0, 0);
                    acc2[mt2][nt] = __builtin_amdgcn_mfma_f32_16x16x32_bf16(al2[mt2], bh, acc2[mt2][nt], 0, 0, 0);
                    acc2[mt2][nt] = __builtin_amdgcn_mfma_f32_16x16x32_bf16(al2[mt2], bl, acc2[mt2][nt], 0, 0, 0);
                }
            }
        }
        __syncthreads();
    }

    float part[4] = {0.f, 0.f, 0.f, 0.f};
#pragma unroll
    for (int mt2 = 0; mt2 < 2; ++mt2) {
        int ob = (w << 5) + (mt2 << 4) + ((lane >> 4) << 2);
#pragma unroll
        for (int nt = 0; nt < 4; ++nt) {
#pragma unroll
            for (int r = 0; r < 4; ++r) {
                int o = ob + r;
                float a2v = lrelu(sB[o] * acc2[mt2][nt][r] + tB[o]);
                part[nt] += w3s[o] * a2v;
            }
        }
    }
#pragma unroll
    for (int nt = 0; nt < 4; ++nt) {
        part[nt] += __shfl_xor(part[nt], 16);
        part[nt] += __shfl_xor(part[nt], 32);
    }
    if (lane < 16) {
#pragma unroll
        for (int nt = 0; nt < 4; ++nt)
            outp[w][(nt << 4) + lane] = part[nt];
    }
    __syncthreads();
    if (t < 64)
        out[b * N_ + n0 + t] = outp[0][t] + outp[1][t] + outp[2][t] + outp[3][t] + b3[0];
}

// ---------------------------------------------------------------------------
extern "C" void kernel_launch(void* const* d_in, const int* in_sizes, int n_in,
                              void* d_out, int out_size, void* d_ws, size_t ws_size,
                              hipStream_t stream) {
    (void)in_sizes; (void)n_in; (void)out_size; (void)ws_size;
    const float* x    = (const float*)d_in[0];
    const float* wk1  = (const float*)d_in[1];
    const float* gk1  = (const float*)d_in[2];
    const float* bk1  = (const float*)d_in[3];
    const float* mk1  = (const float*)d_in[4];
    const float* vk1  = (const float*)d_in[5];
    const float* wk2  = (const float*)d_in[6];
    const float* gk2  = (const float*)d_in[7];
    const float* bk2  = (const float*)d_in[8];
    const float* mk2  = (const float*)d_in[9];
    const float* vk2  = (const float*)d_in[10];
    const float* w1   = (const float*)d_in[11];
    const float* g1   = (const float*)d_in[12];
    const float* b1   = (const float*)d_in[13];
    const float* m1   = (const float*)d_in[14];
    const float* v1   = (const float*)d_in[15];
    const float* w2   = (const float*)d_in[16];
    const float* g2   = (const float*)d_in[17];
    const float* b2   = (const float*)d_in[18];
    const float* m2   = (const float*)d_in[19];
    const float* v2   = (const float*)d_in[20];
    const float* w3   = (const float*)d_in[21];
    const float* b3   = (const float*)d_in[22];

    char* ws = (char*)d_ws;
    float* yA  = (float*)(ws);                       //  8 MB
    float* dd  = (float*)(ws + 8388608);             //  8 MB
    float* xx  = (float*)(ws + 16777216);            //  128 KB
    int*   idx = (int*)  (ws + 16908288);            //  2.5 MB
    float* ht  = (float*)(ws + 19529728);            //  8 MB
    unsigned short* xps = (unsigned short*)(ws + 27918336);  // 8 MB split-bf16 images

    k_pre <<<B_ * (N_ / 64), 256, 0, stream>>>(x, wk1, yA, dd, xx, xps);
    k_topk<<<B_ * (N_ / 32), 512, 0, stream>>>(xps, xx, idx);
    k_edge<<<B_ * (N_ / 8),  256, 0, stream>>>(yA, dd, idx, wk2,
                                               gk1, bk1, mk1, vk1,
                                               gk2, bk2, mk2, vk2, ht);
    k_head<<<B_ * (N_ / 64), 256, 0, stream>>>(ht, w1, g1, b1, m1, v1,
                                               w2, g2, b2, m2, v2, w3, b3,
                                               (float*)d_out);
}

// Round 16
// 295.519 us; speedup vs baseline: 1.0540x; 1.0540x over previous
//
#include <hip/hip_runtime.h>
#include <hip/hip_bf16.h>

#define B_ 8
#define C_ 64
#define N_ 4096
#define K_ 20
#define EPS_ 1e-5f
#define SLOPE_ 0.2f

typedef __attribute__((ext_vector_type(8))) short bf16x8;
typedef __attribute__((ext_vector_type(4))) float f32x4;

__device__ __forceinline__ float lrelu(float x) { return x >= 0.f ? x : SLOPE_ * x; }
__device__ __forceinline__ float bf2f(unsigned short u) {
    return __uint_as_float(((unsigned int)u) << 16);
}
__device__ __forceinline__ unsigned short f2bf(float f) {
    unsigned int u = __float_as_uint(f);
    return (unsigned short)((u + 0x7FFFu + ((u >> 16) & 1u)) >> 16);
}

__device__ __forceinline__ float rdlanef(float x, int l) {
    return __int_as_float(__builtin_amdgcn_readlane(__float_as_int(x), l));
}

// split 8 floats into hi/lo bf16x8
__device__ __forceinline__ void split8(const float* v, bf16x8& h, bf16x8& l) {
#pragma unroll
    for (int j = 0; j < 8; ++j) {
        unsigned short hh = f2bf(v[j]);
        h[j] = (short)hh;
        l[j] = (short)f2bf(v[j] - bf2f(hh));
    }
}

// ---------------------------------------------------------------------------
// Kernel A (MFMA): Y[128x64] = [wA;wB] @ xs via split-bf16 MFMA.
// yA = rows 0..63; dd = rows 64..127 - rows 0..63. Also xx and xps images.
// grid 512 (B * N/64), block 256
// ---------------------------------------------------------------------------
__global__ void __launch_bounds__(256) k_pre(const float* __restrict__ x,
                                             const float* __restrict__ wk1,
                                             float* __restrict__ yA,
                                             float* __restrict__ dd,
                                             float* __restrict__ xx,
                                             unsigned short* __restrict__ xps) {
    __shared__ float xs[64][64];
    __shared__ unsigned short wimg[16384];
    __shared__ unsigned short ximg[8192];
    int t = threadIdx.x;
    int lane = t & 63;
    int w = t >> 6;
    int blk = blockIdx.x;
    int b = blk >> 6;
    int n0 = (blk & 63) << 6;

    const float* xb = x + (size_t)b * C_ * N_;
    for (int i = 0; i < 4; ++i) {
        int j = i * 256 + t;
        int c = j >> 4;
        int p4 = (j & 15) << 2;
        float4 v = *(const float4*)(xb + c * N_ + n0 + p4);
        xs[c][p4 + 0] = v.x; xs[c][p4 + 1] = v.y;
        xs[c][p4 + 2] = v.z; xs[c][p4 + 3] = v.w;
    }
    for (int rep = 0; rep < 4; ++rep) {
        int i = rep * 256 + t;
        int m = i >> 3, oct = i & 7;
        const float* src = wk1 + (m & 63) * 128 + ((m >> 6) << 6) + oct * 8;
        float4 a4 = *(const float4*)src;
        float4 b4 = *(const float4*)(src + 4);
        float wv[8] = {a4.x, a4.y, a4.z, a4.w, b4.x, b4.y, b4.z, b4.w};
        bf16x8 hv, lv8;
        split8(wv, hv, lv8);
        int unit = oct ^ (m & 7);
        *(bf16x8*)&wimg[m * 64 + unit * 8] = hv;
        *(bf16x8*)&wimg[8192 + m * 64 + unit * 8] = lv8;
    }
    __syncthreads();

    if (t < 64) {
        float s = 0.f;
        for (int c = 0; c < 64; ++c) { float xv = xs[c][t]; s += xv * xv; }
        xx[b * N_ + n0 + t] = s;
    }

    unsigned short* xc = xps + ((size_t)(b * 64 + (blk & 63))) * 8192;
#pragma unroll
    for (int q = 0; q < 2; ++q) {
        int i = q * 256 + t;
        int nl = i >> 3, oct = i & 7;
        float wv[8];
#pragma unroll
        for (int j = 0; j < 8; ++j) wv[j] = xs[oct * 8 + j][nl];
        bf16x8 hv, lv8;
        split8(wv, hv, lv8);
        int unit = oct ^ (nl & 7);
        *(bf16x8*)&ximg[nl * 64 + unit * 8] = hv;
        *(bf16x8*)&ximg[4096 + nl * 64 + unit * 8] = lv8;
        *(bf16x8*)&xc[nl * 64 + unit * 8] = hv;
        *(bf16x8*)&xc[4096 + nl * 64 + unit * 8] = lv8;
    }
    __syncthreads();

    int mA = (w << 4) + (lane & 15);
    int mB = ((w + 4) << 4) + (lane & 15);
    bf16x8 ahA[2], alA[2], ahB[2], alB[2];
#pragma unroll
    for (int kc = 0; kc < 2; ++kc) {
        int uA = (kc * 4 + (lane >> 4)) ^ (mA & 7);
        int uB = (kc * 4 + (lane >> 4)) ^ (mB & 7);
        ahA[kc] = *(const bf16x8*)&wimg[mA * 64 + uA * 8];
        alA[kc] = *(const bf16x8*)&wimg[8192 + mA * 64 + uA * 8];
        ahB[kc] = *(const bf16x8*)&wimg[mB * 64 + uB * 8];
        alB[kc] = *(const bf16x8*)&wimg[8192 + mB * 64 + uB * 8];
    }
    size_t pbase = (size_t)(b * N_ + n0);
#pragma unroll
    for (int nt = 0; nt < 4; ++nt) {
        int p = nt * 16 + (lane & 15);
        int u0 = ((lane >> 4)) ^ (p & 7);
        int u1 = (4 + (lane >> 4)) ^ (p & 7);
        bf16x8 bh0 = *(const bf16x8*)&ximg[p * 64 + u0 * 8];
        bf16x8 bl0 = *(const bf16x8*)&ximg[4096 + p * 64 + u0 * 8];
        bf16x8 bh1 = *(const bf16x8*)&ximg[p * 64 + u1 * 8];
        bf16x8 bl1 = *(const bf16x8*)&ximg[4096 + p * 64 + u1 * 8];
        f32x4 aA = {0.f, 0.f, 0.f, 0.f};
        aA = __builtin_amdgcn_mfma_f32_16x16x32_bf16(ahA[0], bh0, aA, 0, 0, 0);
        aA = __builtin_amdgcn_mfma_f32_16x16x32_bf16(ahA[0], bl0, aA, 0, 0, 0);
        aA = __builtin_amdgcn_mfma_f32_16x16x32_bf16(alA[0], bh0, aA, 0, 0, 0);
        aA = __builtin_amdgcn_mfma_f32_16x16x32_bf16(alA[0], bl0, aA, 0, 0, 0);
        aA = __builtin_amdgcn_mfma_f32_16x16x32_bf16(ahA[1], bh1, aA, 0, 0, 0);
        aA = __builtin_amdgcn_mfma_f32_16x16x32_bf16(ahA[1], bl1, aA, 0, 0, 0);
        aA = __builtin_amdgcn_mfma_f32_16x16x32_bf16(alA[1], bh1, aA, 0, 0, 0);
        aA = __builtin_amdgcn_mfma_f32_16x16x32_bf16(alA[1], bl1, aA, 0, 0, 0);
        f32x4 aB = {0.f, 0.f, 0.f, 0.f};
        aB = __builtin_amdgcn_mfma_f32_16x16x32_bf16(ahB[0], bh0, aB, 0, 0, 0);
        aB = __builtin_amdgcn_mfma_f32_16x16x32_bf16(ahB[0], bl0, aB, 0, 0, 0);
        aB = __builtin_amdgcn_mfma_f32_16x16x32_bf16(alB[0], bh0, aB, 0, 0, 0);
        aB = __builtin_amdgcn_mfma_f32_16x16x32_bf16(alB[0], bl0, aB, 0, 0, 0);
        aB = __builtin_amdgcn_mfma_f32_16x16x32_bf16(ahB[1], bh1, aB, 0, 0, 0);
        aB = __builtin_amdgcn_mfma_f32_16x16x32_bf16(ahB[1], bl1, aB, 0, 0, 0);
        aB = __builtin_amdgcn_mfma_f32_16x16x32_bf16(alB[1], bh1, aB, 0, 0, 0);
        aB = __builtin_amdgcn_mfma_f32_16x16x32_bf16(alB[1], bl1, aB, 0, 0, 0);

        int obase = (w << 4) + ((lane >> 4) << 2);
        float4 ya4 = {aA[0], aA[1], aA[2], aA[3]};
        float4 dd4 = {aB[0] - aA[0], aB[1] - aA[1], aB[2] - aA[2], aB[3] - aA[3]};
        *(float4*)(yA + (pbase + p) * 64 + obase) = ya4;
        *(float4*)(dd + (pbase + p) * 64 + obase) = dd4;
    }
}

// ---------------------------------------------------------------------------
// Kernel B: top-20 neighbors. Round-14 sequential insert (proven), with a
// 4-slot score buffer and selection+barrier every 2 chunks (32 barriers).
// Slot hazard check: window (2p,2p+1) writes {2p,2p+1}&3, reads {2p-2,2p-1}&3
// — disjoint mod 4. Per-row candidate order bit-identical to round 13/14.
// ---------------------------------------------------------------------------
__global__ void __launch_bounds__(512) k_topk(const unsigned short* __restrict__ xps,
                                              const float* __restrict__ xx,
                                              int* __restrict__ idxg) {
    __shared__ float sc[4][32][68];
    int t = threadIdx.x;
    int lane = t & 63;
    int w = t >> 6;
    int wr = w >> 2;
    int wc = w & 3;
    int blk = blockIdx.x;
    int b = blk >> 7;
    int n0 = (blk & 127) << 5;
    int bc = b << 6;
    const float* xxb = xx + b * N_;
    int pa = ((lane + 1) & 63) << 2;

    const unsigned short* xcA = xps + ((size_t)(bc + ((blk & 127) >> 1))) * 8192;
    int anl = ((blk & 1) << 5) + (wr << 4) + (lane & 15);
    bf16x8 ah[2], al[2];
#pragma unroll
    for (int kc = 0; kc < 2; ++kc) {
        int unit = (kc * 4 + (lane >> 4)) ^ (anl & 7);
        ah[kc] = *(const bf16x8*)&xcA[anl * 64 + unit * 8];
        al[kc] = *(const bf16x8*)&xcA[4096 + anl * 64 + unit * 8];
    }

    int n_ = (wc << 4) + (lane & 15);
    int off0 = n_ * 64 + (((lane >> 4)) ^ (n_ & 7)) * 8;
    int off1 = n_ * 64 + ((4 + (lane >> 4)) ^ (n_ & 7)) * 8;

    float lv[4];
    int   li[4];
#pragma unroll
    for (int i = 0; i < 4; ++i) { lv[i] = -3.0e38f; li[i] = 0; }

    // sorted insert; no in-loop threshold recheck (no-op inserts are exact)
    auto ins = [&](float& lvr, int& lir, float s, int m0) {
        float mnc = rdlanef(lvr, 19);
        unsigned long long mask = __ballot(s > mnc);
        while (mask) {
            int j = (int)__builtin_ctzll(mask);
            mask &= mask - 1;
            float sv = rdlanef(s, j);
            unsigned long long gt = __ballot(lane < 20 && lvr > sv);
            int cpos = __popcll(gt);
            float upv = __int_as_float(
                __builtin_amdgcn_ds_permute(pa, __float_as_int(lvr)));
            int   upi = __builtin_amdgcn_ds_permute(pa, lir);
            if (lane >= cpos && lane < 20) {
                lvr = (lane == cpos) ? sv : upv;
                lir = (lane == cpos) ? (m0 + j) : upi;
            }
        }
    };

    auto sel4 = [&](int buf, int m0) {
#pragma unroll
        for (int i = 0; i < 4; ++i) {
            int lrow = (w << 2) + i;
            float s = sc[buf][lrow][lane];
            ins(lv[i], li[i], s, m0);
        }
    };

    const unsigned short* xcB = xps + (size_t)bc * 8192;
    bf16x8 bh0 = *(const bf16x8*)&xcB[off0];
    bf16x8 bl0 = *(const bf16x8*)&xcB[4096 + off0];
    bf16x8 bh1 = *(const bf16x8*)&xcB[off1];
    bf16x8 bl1 = *(const bf16x8*)&xcB[4096 + off1];
    float xxv = xxb[n_];

    for (int mc = 0; mc < 64; ++mc) {
        f32x4 acc = {0.f, 0.f, 0.f, 0.f};
        acc = __builtin_amdgcn_mfma_f32_16x16x32_bf16(ah[0], bh0, acc, 0, 0, 0);
        acc = __builtin_amdgcn_mfma_f32_16x16x32_bf16(ah[0], bl0, acc, 0, 0, 0);
        acc = __builtin_amdgcn_mfma_f32_16x16x32_bf16(al[0], bh0, acc, 0, 0, 0);
        acc = __builtin_amdgcn_mfma_f32_16x16x32_bf16(al[0], bl0, acc, 0, 0, 0);
        acc = __builtin_amdgcn_mfma_f32_16x16x32_bf16(ah[1], bh1, acc, 0, 0, 0);
        acc = __builtin_amdgcn_mfma_f32_16x16x32_bf16(ah[1], bl1, acc, 0, 0, 0);
        acc = __builtin_amdgcn_mfma_f32_16x16x32_bf16(al[1], bh1, acc, 0, 0, 0);
        acc = __builtin_amdgcn_mfma_f32_16x16x32_bf16(al[1], bl1, acc, 0, 0, 0);

#pragma unroll
        for (int r = 0; r < 4; ++r)
            sc[mc & 3][(wr << 4) + ((lane >> 4) << 2) + r][n_] = 2.f * acc[r] - xxv;

        if (mc + 1 < 64) {
            const unsigned short* xn2 = xps + (size_t)(bc + mc + 1) * 8192;
            bh0 = *(const bf16x8*)&xn2[off0];
            bl0 = *(const bf16x8*)&xn2[4096 + off0];
            bh1 = *(const bf16x8*)&xn2[off1];
            bl1 = *(const bf16x8*)&xn2[4096 + off1];
            xxv = xxb[((mc + 1) << 6) + n_];
        }

        if (mc & 1) {
            if (mc >= 3) {
                sel4((mc - 3) & 3, (mc - 3) << 6);
                sel4((mc - 2) & 3, (mc - 2) << 6);
            }
            __syncthreads();
        }
    }

    // tail: chunks 62, 63 (slots 2, 3); barrier at mc=63 end covered them
    sel4(2, 62 << 6);
    sel4(3, 63 << 6);

#pragma unroll
    for (int i = 0; i < 4; ++i) {
        int n = n0 + (w << 2) + i;
        if (lane < K_)
            idxg[((size_t)(b * N_ + n)) * K_ + lane] = li[i];
    }
}

// ---------------------------------------------------------------------------
// Kernel C1 (MFMA): gather+BN1 -> split-bf16 images -> MFMA GEMM
// (unchanged — proven)
// ---------------------------------------------------------------------------
__global__ void __launch_bounds__(256) k_edge(const float* __restrict__ yA,
                                              const float* __restrict__ dd,
                                              const int* __restrict__ idxg,
                                              const float* __restrict__ wk2,
                                              const float* __restrict__ g1,
                                              const float* __restrict__ bb1,
                                              const float* __restrict__ mm1,
                                              const float* __restrict__ vv1,
                                              const float* __restrict__ g2,
                                              const float* __restrict__ bb2,
                                              const float* __restrict__ mm2,
                                              const float* __restrict__ vv2,
                                              float* __restrict__ ht) {
    __shared__ unsigned short wimg[8192];
    __shared__ float ubuf[64 * 164];
    __shared__ float s1c[64], t1c[64], s2c[64], t2c[64];
    __shared__ float ddl[8][64];
    __shared__ int   il[8][K_];
    __shared__ float hl[8][64];
    unsigned short* timgH = (unsigned short*)ubuf;
    unsigned short* timgL = timgH + 160 * 64;
    float* ct = ubuf;

    int t = threadIdx.x;
    int lane = t & 63;
    int w = t >> 6;
    int blk = blockIdx.x;
    int b = blk >> 9;
    int n0 = (blk & 511) << 3;

    for (int rep = 0; rep < 2; ++rep) {
        int i = rep * 256 + t;
        int row = i >> 3, oct = i & 7;
        float4 wa = *(const float4*)(wk2 + row * 64 + oct * 8);
        float4 wb = *(const float4*)(wk2 + row * 64 + oct * 8 + 4);
        float wv[8] = {wa.x, wa.y, wa.z, wa.w, wb.x, wb.y, wb.z, wb.w};
        bf16x8 hv, lv8;
        split8(wv, hv, lv8);
        int unit = oct ^ (row & 7);
        *(bf16x8*)&wimg[row * 64 + unit * 8] = hv;
        *(bf16x8*)&wimg[4096 + row * 64 + unit * 8] = lv8;
    }
    if (t < 64) {
        float g = g1[t], be = bb1[t], m = mm1[t], v = vv1[t];
        float s = g * rsqrtf(v + EPS_);
        s1c[t] = s; t1c[t] = be - m * s;
        g = g2[t]; be = bb2[t]; m = mm2[t]; v = vv2[t];
        s = g * rsqrtf(v + EPS_);
        s2c[t] = s; t2c[t] = be - m * s;
    }
    size_t pbase = (size_t)(b * N_ + n0);
    for (int i = t; i < 512; i += 256) {
        int pt = i >> 6, o = i & 63;
        ddl[pt][o] = dd[(pbase + pt) * 64 + o];
    }
    if (t < 8 * K_) {
        int pt = t / K_, k = t % K_;
        il[pt][k] = idxg[(pbase + pt) * K_ + k];
    }
    __syncthreads();

    const float* yAb = yA + (size_t)(b * N_) * 64;
    float4 ga[5][2];
    int gcol[5], goct[5], gpt[5];
#pragma unroll
    for (int rep = 0; rep < 5; ++rep) {
        int j = rep * 256 + t;
        int pt = j / 160;
        int r = j - pt * 160;
        int k = r >> 3, oct = r & 7;
        int m = il[pt][k];
        const float* src = yAb + (size_t)m * 64 + oct * 8;
        ga[rep][0] = *(const float4*)src;
        ga[rep][1] = *(const float4*)(src + 4);
        gcol[rep] = pt * 20 + k; goct[rep] = oct; gpt[rep] = pt;
    }
#pragma unroll
    for (int rep = 0; rep < 5; ++rep) {
        int oct = goct[rep], pt = gpt[rep], col = gcol[rep];
        float yv[8] = {ga[rep][0].x, ga[rep][0].y, ga[rep][0].z, ga[rep][0].w,
                       ga[rep][1].x, ga[rep][1].y, ga[rep][1].z, ga[rep][1].w};
        float tv[8];
#pragma unroll
        for (int jj = 0; jj < 8; ++jj) {
            int oc = oct * 8 + jj;
            tv[jj] = lrelu(s1c[oc] * (yv[jj] + ddl[pt][oc]) + t1c[oc]);
        }
        bf16x8 hv, lv8;
        split8(tv, hv, lv8);
        int unit = oct ^ (col & 7);
        *(bf16x8*)&timgH[col * 64 + unit * 8] = hv;
        *(bf16x8*)&timgL[col * 64 + unit * 8] = lv8;
    }
    __syncthreads();

    int anl = (w << 4) + (lane & 15);
    bf16x8 ah[2], al[2];
#pragma unroll
    for (int kc = 0; kc < 2; ++kc) {
        int unit = (kc * 4 + (lane >> 4)) ^ (anl & 7);
        ah[kc] = *(const bf16x8*)&wimg[anl * 64 + unit * 8];
        al[kc] = *(const bf16x8*)&wimg[4096 + anl * 64 + unit * 8];
    }
    f32x4 acc[10];
#pragma unroll
    for (int nt = 0; nt < 10; ++nt) {
        int col = nt * 16 + (lane & 15);
        int u0 = ((lane >> 4)) ^ (col & 7);
        int u1 = (4 + (lane >> 4)) ^ (col & 7);
        bf16x8 bh0 = *(const bf16x8*)&timgH[col * 64 + u0 * 8];
        bf16x8 bl0 = *(const bf16x8*)&timgL[col * 64 + u0 * 8];
        bf16x8 bh1 = *(const bf16x8*)&timgH[col * 64 + u1 * 8];
        bf16x8 bl1 = *(const bf16x8*)&timgL[col * 64 + u1 * 8];
        f32x4 a = {0.f, 0.f, 0.f, 0.f};
        a = __builtin_amdgcn_mfma_f32_16x16x32_bf16(ah[0], bh0, a, 0, 0, 0);
        a = __builtin_amdgcn_mfma_f32_16x16x32_bf16(ah[0], bl0, a, 0, 0, 0);
        a = __builtin_amdgcn_mfma_f32_16x16x32_bf16(al[0], bh0, a, 0, 0, 0);
        a = __builtin_amdgcn_mfma_f32_16x16x32_bf16(al[0], bl0, a, 0, 0, 0);
        a = __builtin_amdgcn_mfma_f32_16x16x32_bf16(ah[1], bh1, a, 0, 0, 0);
        a = __builtin_amdgcn_mfma_f32_16x16x32_bf16(ah[1], bl1, a, 0, 0, 0);
        a = __builtin_amdgcn_mfma_f32_16x16x32_bf16(al[1], bh1, a, 0, 0, 0);
        a = __builtin_amdgcn_mfma_f32_16x16x32_bf16(al[1], bl1, a, 0, 0, 0);
        acc[nt] = a;
    }
    __syncthreads();

#pragma unroll
    for (int nt = 0; nt < 10; ++nt) {
#pragma unroll
        for (int r = 0; r < 4; ++r)
            ct[((w << 4) + ((lane >> 4) << 2) + r) * 164 + nt * 16 + (lane & 15)] =
                acc[nt][r];
    }
    __syncthreads();

#pragma unroll
    for (int rep = 0; rep < 2; ++rep) {
        int pair = rep * 256 + t;
        int o2 = pair >> 3, pt = pair & 7;
        const float* row = &ct[o2 * 164 + pt * 20];
        float4 c0 = *(const float4*)(row + 0);
        float4 c1 = *(const float4*)(row + 4);
        float4 c2 = *(const float4*)(row + 8);
        float4 c3 = *(const float4*)(row + 12);
        float4 c4 = *(const float4*)(row + 16);
        float mx = fmaxf(fmaxf(fmaxf(c0.x, c0.y), fmaxf(c0.z, c0.w)),
                   fmaxf(fmaxf(fmaxf(c1.x, c1.y), fmaxf(c1.z, c1.w)),
                   fmaxf(fmaxf(fmaxf(c2.x, c2.y), fmaxf(c2.z, c2.w)),
                   fmaxf(fmaxf(fmaxf(c3.x, c3.y), fmaxf(c3.z, c3.w)),
                         fmaxf(fmaxf(c4.x, c4.y), fmaxf(c4.z, c4.w))))));
        hl[pt][o2] = lrelu(s2c[o2] * mx + t2c[o2]);
    }
    __syncthreads();

    float* htb = ht + (size_t)b * 64 * N_;
    for (int i = t; i < 512; i += 256) {
        int o = i >> 3, pt2 = i & 7;
        htb[o * N_ + n0 + pt2] = hl[pt2][o];
    }
}

// ---------------------------------------------------------------------------
// Kernel C2 (MFMA): head 64 -> 256 -> 128 -> 1 (unchanged — proven)
// ---------------------------------------------------------------------------
__global__ void __launch_bounds__(256) k_head(const float* __restrict__ ht,
                                              const float* __restrict__ w1,
                                              const float* __restrict__ g1,
                                              const float* __restrict__ bb1,
                                              const float* __restrict__ mm1,
                                              const float* __restrict__ vv1,
                                              const float* __restrict__ w2,
                                              const float* __restrict__ g2,
                                              const float* __restrict__ bb2,
                                              const float* __restrict__ mm2,
                                              const float* __restrict__ vv2,
                                              const float* __restrict__ w3,
                                              const float* __restrict__ b3,
                                              float* __restrict__ out) {
    __shared__ unsigned int himgH[64 * 36];
    __shared__ unsigned int himgL[64 * 36];
    __shared__ float a1f[64 * 132];
    __shared__ float sA[256], tA[256], sB[128], tB[128], w3s[128];
    __shared__ float outp[4][64];
    int t = threadIdx.x;
    int lane = t & 63;
    int w = t >> 6;
    int blk = blockIdx.x;
    int b = blk >> 6;
    int n0 = (blk & 63) << 6;
    const float* htb = ht + (size_t)b * 64 * N_;

#pragma unroll
    for (int rep = 0; rep < 8; ++rep) {
        int i = rep * 256 + t;
        int pt = i & 63, op = i >> 6;
        float v0 = htb[(2 * op) * N_ + n0 + pt];
        float v1 = htb[(2 * op + 1) * N_ + n0 + pt];
        unsigned short h0 = f2bf(v0), h1 = f2bf(v1);
        unsigned short l0 = f2bf(v0 - bf2f(h0)), l1 = f2bf(v1 - bf2f(h1));
        himgH[pt * 36 + op] = (unsigned int)h0 | ((unsigned int)h1 << 16);
        himgL[pt * 36 + op] = (unsigned int)l0 | ((unsigned int)l1 << 16);
    }
    {
        float g = g1[t], be = bb1[t], m = mm1[t], v = vv1[t];
        float s = g * rsqrtf(v + EPS_);
        sA[t] = s; tA[t] = be - m * s;
    }
    if (t < 128) {
        float g = g2[t], be = bb2[t], m = mm2[t], v = vv2[t];
        float s = g * rsqrtf(v + EPS_);
        sB[t] = s; tB[t] = be - m * s;
        w3s[t] = w3[t];
    }
    __syncthreads();

    f32x4 acc2[2][4];
#pragma unroll
    for (int i = 0; i < 2; ++i)
#pragma unroll
        for (int j = 0; j < 4; ++j) acc2[i][j] = (f32x4){0.f, 0.f, 0.f, 0.f};

    for (int ka = 0; ka < 2; ++ka) {
        bf16x8 wh[2][2], wl[2][2];
#pragma unroll
        for (int mtl2 = 0; mtl2 < 2; ++mtl2) {
            int mabs = 128 * ka + ((2 * w + mtl2) << 4) + (lane & 15);
#pragma unroll
            for (int kc = 0; kc < 2; ++kc) {
                const float* p = w1 + mabs * 64 + kc * 32 + ((lane >> 4) << 3);
                float4 q0 = *(const float4*)p;
                float4 q1 = *(const float4*)(p + 4);
                float vv8[8] = {q0.x, q0.y, q0.z, q0.w, q1.x, q1.y, q1.z, q1.w};
                split8(vv8, wh[mtl2][kc], wl[mtl2][kc]);
            }
        }
#pragma unroll
        for (int nt = 0; nt < 4; ++nt) {
            int pt = (nt << 4) + (lane & 15);
            f32x4 aAcc[2] = {{0.f, 0.f, 0.f, 0.f}, {0.f, 0.f, 0.f, 0.f}};
#pragma unroll
            for (int kc = 0; kc < 2; ++kc) {
                int chb = kc * 32 + ((lane >> 4) << 3);
                bf16x8 bh = *(const bf16x8*)((const unsigned short*)himgH + pt * 72 + chb);
                bf16x8 bl = *(const bf16x8*)((const unsigned short*)himgL + pt * 72 + chb);
#pragma unroll
                for (int mtl2 = 0; mtl2 < 2; ++mtl2) {
                    aAcc[mtl2] = __builtin_amdgcn_mfma_f32_16x16x32_bf16(wh[mtl2][kc], bh, aAcc[mtl2], 0, 0, 0);
                    aAcc[mtl2] = __builtin_amdgcn_mfma_f32_16x16x32_bf16(wh[mtl2][kc], bl, aAcc[mtl2], 0, 0, 0);
                    aAcc[mtl2] = __builtin_amdgcn_mfma_f32_16x16x32_bf16(wl[mtl2][kc], bh, aAcc[mtl2], 0, 0, 0);
                    aAcc[mtl2] = __builtin_amdgcn_mfma_f32_16x16x32_bf16(wl[mtl2][kc], bl, aAcc[mtl2], 0, 0, 0);
                }
            }
#pragma unroll
            for (int mtl2 = 0; mtl2 < 2; ++mtl2) {
                int klocal = ((2 * w + mtl2) << 4) + ((lane >> 4) << 2);
                int rabs = 128 * ka + klocal;
                float4 ov;
                ov.x = lrelu(sA[rabs + 0] * aAcc[mtl2][0] + tA[rabs + 0]);
                ov.y = lrelu(sA[rabs + 1] * aAcc[mtl2][1] + tA[rabs + 1]);
                ov.z = lrelu(sA[rabs + 2] * aAcc[mtl2][2] + tA[rabs + 2]);
                ov.w = lrelu(sA[rabs + 3] * aAcc[mtl2][3] + tA[rabs + 3]);
                *(float4*)&a1f[pt * 132 + klocal] = ov;
            }
        }
        __syncthreads();

#pragma unroll
        for (int kc2 = 0; kc2 < 4; ++kc2) {
            bf16x8 ah2[2], al2[2];
#pragma unroll
            for (int mt2 = 0; mt2 < 2; ++mt2) {
                int oabs = (w << 5) + (mt2 << 4) + (lane & 15);
                const float* p = w2 + oabs * 256 + 128 * ka + kc2 * 32 + ((lane >> 4) << 3);
                float4 q0 = *(const float4*)p;
                float4 q1 = *(const float4*)(p + 4);
                float vv8[8] = {q0.x, q0.y, q0.z, q0.w, q1.x, q1.y, q1.z, q1.w};
                split8(vv8, ah2[mt2], al2[mt2]);
            }
#pragma unroll
            for (int nt = 0; nt < 4; ++nt) {
                int pt = (nt << 4) + (lane & 15);
                int kl = kc2 * 32 + ((lane >> 4) << 3);
                float4 q0 = *(const float4*)&a1f[pt * 132 + kl];
                float4 q1 = *(const float4*)&a1f[pt * 132 + kl + 4];
                float vv8[8] = {q0.x, q0.y, q0.z, q0.w, q1.x, q1.y, q1.z, q1.w};
                bf16x8 bh, bl;
                split8(vv8, bh, bl);
#pragma unroll
                for (int mt2 = 0; mt2 < 2; ++mt2) {
                    acc2[mt2][nt] = __builtin_amdgcn_mfma_f32_16x16x32_bf16(ah2[mt2], bh, acc2[mt2][nt], 0, 0, 0);
                    acc2[mt2][nt] = __builtin_amdgcn_mfma_f32_16x16x32_bf16(ah2[mt2], bl, acc2[mt2][nt], 0, 0, 0);
                    acc2[mt2][nt] = __builtin_amdgcn_mfma_f32_16x16x32_bf16(al2[mt2], bh, acc2[mt2][nt], 0, 0, 0);
                    acc2[mt2][nt] = __builtin_amdgcn_mfma_f32_16x16x32_bf16(al2[mt2], bl, acc2[mt2][nt], 0, 0, 0);
                }
            }
        }
        __syncthreads();
    }

    float part[4] = {0.f, 0.f, 0.f, 0.f};
#pragma unroll
    for (int mt2 = 0; mt2 < 2; ++mt2) {
        int ob = (w << 5) + (mt2 << 4) + ((lane >> 4) << 2);
#pragma unroll
        for (int nt = 0; nt < 4; ++nt) {
#pragma unroll
            for (int r = 0; r < 4; ++r) {
                int o = ob + r;
                float a2v = lrelu(sB[o] * acc2[mt2][nt][r] + tB[o]);
                part[nt] += w3s[o] * a2v;
            }
        }
    }
#pragma unroll
    for (int nt = 0; nt < 4; ++nt) {
        part[nt] += __shfl_xor(part[nt], 16);
        part[nt] += __shfl_xor(part[nt], 32);
    }
    if (lane < 16) {
#pragma unroll
        for (int nt = 0; nt < 4; ++nt)
            outp[w][(nt << 4) + lane] = part[nt];
    }
    __syncthreads();
    if (t < 64)
        out[b * N_ + n0 + t] = outp[0][t] + outp[1][t] + outp[2][t] + outp[3][t] + b3[0];
}

// ---------------------------------------------------------------------------
extern "C" void kernel_launch(void* const* d_in, const int* in_sizes, int n_in,
                              void* d_out, int out_size, void* d_ws, size_t ws_size,
                              hipStream_t stream) {
    (void)in_sizes; (void)n_in; (void)out_size; (void)ws_size;
    const float* x    = (const float*)d_in[0];
    const float* wk1  = (const float*)d_in[1];
    const float* gk1  = (const float*)d_in[2];
    const float* bk1  = (const float*)d_in[3];
    const float* mk1  = (const float*)d_in[4];
    const float* vk1  = (const float*)d_in[5];
    const float* wk2  = (const float*)d_in[6];
    const float* gk2  = (const float*)d_in[7];
    const float* bk2  = (const float*)d_in[8];
    const float* mk2  = (const float*)d_in[9];
    const float* vk2  = (const float*)d_in[10];
    const float* w1   = (const float*)d_in[11];
    const float* g1   = (const float*)d_in[12];
    const float* b1   = (const float*)d_in[13];
    const float* m1   = (const float*)d_in[14];
    const float* v1   = (const float*)d_in[15];
    const float* w2   = (const float*)d_in[16];
    const float* g2   = (const float*)d_in[17];
    const float* b2   = (const float*)d_in[18];
    const float* m2   = (const float*)d_in[19];
    const float* v2   = (const float*)d_in[20];
    const float* w3   = (const float*)d_in[21];
    const float* b3   = (const float*)d_in[22];

    char* ws = (char*)d_ws;
    float* yA  = (float*)(ws);                       //  8 MB
    float* dd  = (float*)(ws + 8388608);             //  8 MB
    float* xx  = (float*)(ws + 16777216);            //  128 KB
    int*   idx = (int*)  (ws + 16908288);            //  2.5 MB
    float* ht  = (float*)(ws + 19529728);            //  8 MB
    unsigned short* xps = (unsigned short*)(ws + 27918336);  // 8 MB split-bf16 images

    k_pre <<<B_ * (N_ / 64), 256, 0, stream>>>(x, wk1, yA, dd, xx, xps);
    k_topk<<<B_ * (N_ / 32), 512, 0, stream>>>(xps, xx, idx);
    k_edge<<<B_ * (N_ / 8),  256, 0, stream>>>(yA, dd, idx, wk2,
                                               gk1, bk1, mk1, vk1,
                                               gk2, bk2, mk2, vk2, ht);
    k_head<<<B_ * (N_ / 64), 256, 0, stream>>>(ht, w1, g1, b1, m1, v1,
                                               w2, g2, b2, m2, v2, w3, b3,
                                               (float*)d_out);
}

// Round 17
// 295.515 us; speedup vs baseline: 1.0540x; 1.0000x over previous
//
#include <hip/hip_runtime.h>
#include <hip/hip_bf16.h>

#define B_ 8
#define C_ 64
#define N_ 4096
#define K_ 20
#define EPS_ 1e-5f
#define SLOPE_ 0.2f

typedef __attribute__((ext_vector_type(8))) short bf16x8;
typedef __attribute__((ext_vector_type(4))) float f32x4;

__device__ __forceinline__ float lrelu(float x) { return x >= 0.f ? x : SLOPE_ * x; }
__device__ __forceinline__ float bf2f(unsigned short u) {
    return __uint_as_float(((unsigned int)u) << 16);
}
__device__ __forceinline__ unsigned short f2bf(float f) {
    unsigned int u = __float_as_uint(f);
    return (unsigned short)((u + 0x7FFFu + ((u >> 16) & 1u)) >> 16);
}

__device__ __forceinline__ float rdlanef(float x, int l) {
    return __int_as_float(__builtin_amdgcn_readlane(__float_as_int(x), l));
}

// split 8 floats into hi/lo bf16x8
__device__ __forceinline__ void split8(const float* v, bf16x8& h, bf16x8& l) {
#pragma unroll
    for (int j = 0; j < 8; ++j) {
        unsigned short hh = f2bf(v[j]);
        h[j] = (short)hh;
        l[j] = (short)f2bf(v[j] - bf2f(hh));
    }
}

// ---------------------------------------------------------------------------
// Kernel A (MFMA): Y[128x64] = [wA;wB] @ xs via split-bf16 MFMA.
// grid 512 (B * N/64), block 256
// ---------------------------------------------------------------------------
__global__ void __launch_bounds__(256) k_pre(const float* __restrict__ x,
                                             const float* __restrict__ wk1,
                                             float* __restrict__ yA,
                                             float* __restrict__ dd,
                                             float* __restrict__ xx,
                                             unsigned short* __restrict__ xps) {
    __shared__ float xs[64][64];
    __shared__ unsigned short wimg[16384];
    __shared__ unsigned short ximg[8192];
    int t = threadIdx.x;
    int lane = t & 63;
    int w = t >> 6;
    int blk = blockIdx.x;
    int b = blk >> 6;
    int n0 = (blk & 63) << 6;

    const float* xb = x + (size_t)b * C_ * N_;
    for (int i = 0; i < 4; ++i) {
        int j = i * 256 + t;
        int c = j >> 4;
        int p4 = (j & 15) << 2;
        float4 v = *(const float4*)(xb + c * N_ + n0 + p4);
        xs[c][p4 + 0] = v.x; xs[c][p4 + 1] = v.y;
        xs[c][p4 + 2] = v.z; xs[c][p4 + 3] = v.w;
    }
    for (int rep = 0; rep < 4; ++rep) {
        int i = rep * 256 + t;
        int m = i >> 3, oct = i & 7;
        const float* src = wk1 + (m & 63) * 128 + ((m >> 6) << 6) + oct * 8;
        float4 a4 = *(const float4*)src;
        float4 b4 = *(const float4*)(src + 4);
        float wv[8] = {a4.x, a4.y, a4.z, a4.w, b4.x, b4.y, b4.z, b4.w};
        bf16x8 hv, lv8;
        split8(wv, hv, lv8);
        int unit = oct ^ (m & 7);
        *(bf16x8*)&wimg[m * 64 + unit * 8] = hv;
        *(bf16x8*)&wimg[8192 + m * 64 + unit * 8] = lv8;
    }
    __syncthreads();

    if (t < 64) {
        float s = 0.f;
        for (int c = 0; c < 64; ++c) { float xv = xs[c][t]; s += xv * xv; }
        xx[b * N_ + n0 + t] = s;
    }

    unsigned short* xc = xps + ((size_t)(b * 64 + (blk & 63))) * 8192;
#pragma unroll
    for (int q = 0; q < 2; ++q) {
        int i = q * 256 + t;
        int nl = i >> 3, oct = i & 7;
        float wv[8];
#pragma unroll
        for (int j = 0; j < 8; ++j) wv[j] = xs[oct * 8 + j][nl];
        bf16x8 hv, lv8;
        split8(wv, hv, lv8);
        int unit = oct ^ (nl & 7);
        *(bf16x8*)&ximg[nl * 64 + unit * 8] = hv;
        *(bf16x8*)&ximg[4096 + nl * 64 + unit * 8] = lv8;
        *(bf16x8*)&xc[nl * 64 + unit * 8] = hv;
        *(bf16x8*)&xc[4096 + nl * 64 + unit * 8] = lv8;
    }
    __syncthreads();

    int mA = (w << 4) + (lane & 15);
    int mB = ((w + 4) << 4) + (lane & 15);
    bf16x8 ahA[2], alA[2], ahB[2], alB[2];
#pragma unroll
    for (int kc = 0; kc < 2; ++kc) {
        int uA = (kc * 4 + (lane >> 4)) ^ (mA & 7);
        int uB = (kc * 4 + (lane >> 4)) ^ (mB & 7);
        ahA[kc] = *(const bf16x8*)&wimg[mA * 64 + uA * 8];
        alA[kc] = *(const bf16x8*)&wimg[8192 + mA * 64 + uA * 8];
        ahB[kc] = *(const bf16x8*)&wimg[mB * 64 + uB * 8];
        alB[kc] = *(const bf16x8*)&wimg[8192 + mB * 64 + uB * 8];
    }
    size_t pbase = (size_t)(b * N_ + n0);
#pragma unroll
    for (int nt = 0; nt < 4; ++nt) {
        int p = nt * 16 + (lane & 15);
        int u0 = ((lane >> 4)) ^ (p & 7);
        int u1 = (4 + (lane >> 4)) ^ (p & 7);
        bf16x8 bh0 = *(const bf16x8*)&ximg[p * 64 + u0 * 8];
        bf16x8 bl0 = *(const bf16x8*)&ximg[4096 + p * 64 + u0 * 8];
        bf16x8 bh1 = *(const bf16x8*)&ximg[p * 64 + u1 * 8];
        bf16x8 bl1 = *(const bf16x8*)&ximg[4096 + p * 64 + u1 * 8];
        f32x4 aA = {0.f, 0.f, 0.f, 0.f};
        aA = __builtin_amdgcn_mfma_f32_16x16x32_bf16(ahA[0], bh0, aA, 0, 0, 0);
        aA = __builtin_amdgcn_mfma_f32_16x16x32_bf16(ahA[0], bl0, aA, 0, 0, 0);
        aA = __builtin_amdgcn_mfma_f32_16x16x32_bf16(alA[0], bh0, aA, 0, 0, 0);
        aA = __builtin_amdgcn_mfma_f32_16x16x32_bf16(alA[0], bl0, aA, 0, 0, 0);
        aA = __builtin_amdgcn_mfma_f32_16x16x32_bf16(ahA[1], bh1, aA, 0, 0, 0);
        aA = __builtin_amdgcn_mfma_f32_16x16x32_bf16(ahA[1], bl1, aA, 0, 0, 0);
        aA = __builtin_amdgcn_mfma_f32_16x16x32_bf16(alA[1], bh1, aA, 0, 0, 0);
        aA = __builtin_amdgcn_mfma_f32_16x16x32_bf16(alA[1], bl1, aA, 0, 0, 0);
        f32x4 aB = {0.f, 0.f, 0.f, 0.f};
        aB = __builtin_amdgcn_mfma_f32_16x16x32_bf16(ahB[0], bh0, aB, 0, 0, 0);
        aB = __builtin_amdgcn_mfma_f32_16x16x32_bf16(ahB[0], bl0, aB, 0, 0, 0);
        aB = __builtin_amdgcn_mfma_f32_16x16x32_bf16(alB[0], bh0, aB, 0, 0, 0);
        aB = __builtin_amdgcn_mfma_f32_16x16x32_bf16(alB[0], bl0, aB, 0, 0, 0);
        aB = __builtin_amdgcn_mfma_f32_16x16x32_bf16(ahB[1], bh1, aB, 0, 0, 0);
        aB = __builtin_amdgcn_mfma_f32_16x16x32_bf16(ahB[1], bl1, aB, 0, 0, 0);
        aB = __builtin_amdgcn_mfma_f32_16x16x32_bf16(alB[1], bh1, aB, 0, 0, 0);
        aB = __builtin_amdgcn_mfma_f32_16x16x32_bf16(alB[1], bl1, aB, 0, 0, 0);

        int obase = (w << 4) + ((lane >> 4) << 2);
        float4 ya4 = {aA[0], aA[1], aA[2], aA[3]};
        float4 dd4 = {aB[0] - aA[0], aB[1] - aA[1], aB[2] - aA[2], aB[3] - aA[3]};
        *(float4*)(yA + (pbase + p) * 64 + obase) = ya4;
        *(float4*)(dd + (pbase + p) * 64 + obase) = dd4;
    }
}

// ---------------------------------------------------------------------------
// Kernel B: top-20 neighbors. 4-slot buffer, 2-chunk barriers (round 16),
// chunk-0 list init via 64-lane bitonic sort (lexicographic (v, -idx) order
// — identical tie semantics to the strictly-greater insertion).
// ---------------------------------------------------------------------------
__global__ void __launch_bounds__(512) k_topk(const unsigned short* __restrict__ xps,
                                              const float* __restrict__ xx,
                                              int* __restrict__ idxg) {
    __shared__ float sc[4][32][68];
    int t = threadIdx.x;
    int lane = t & 63;
    int w = t >> 6;
    int wr = w >> 2;
    int wc = w & 3;
    int blk = blockIdx.x;
    int b = blk >> 7;
    int n0 = (blk & 127) << 5;
    int bc = b << 6;
    const float* xxb = xx + b * N_;
    int pa = ((lane + 1) & 63) << 2;

    const unsigned short* xcA = xps + ((size_t)(bc + ((blk & 127) >> 1))) * 8192;
    int anl = ((blk & 1) << 5) + (wr << 4) + (lane & 15);
    bf16x8 ah[2], al[2];
#pragma unroll
    for (int kc = 0; kc < 2; ++kc) {
        int unit = (kc * 4 + (lane >> 4)) ^ (anl & 7);
        ah[kc] = *(const bf16x8*)&xcA[anl * 64 + unit * 8];
        al[kc] = *(const bf16x8*)&xcA[4096 + anl * 64 + unit * 8];
    }

    int n_ = (wc << 4) + (lane & 15);
    int off0 = n_ * 64 + (((lane >> 4)) ^ (n_ & 7)) * 8;
    int off1 = n_ * 64 + ((4 + (lane >> 4)) ^ (n_ & 7)) * 8;

    float lv[4];
    int   li[4];
#pragma unroll
    for (int i = 0; i < 4; ++i) { lv[i] = -3.0e38f; li[i] = 0; }

    // sorted insert; no in-loop threshold recheck (no-op inserts are exact)
    auto ins = [&](float& lvr, int& lir, float s, int m0) {
        float mnc = rdlanef(lvr, 19);
        unsigned long long mask = __ballot(s > mnc);
        while (mask) {
            int j = (int)__builtin_ctzll(mask);
            mask &= mask - 1;
            float sv = rdlanef(s, j);
            unsigned long long gt = __ballot(lane < 20 && lvr > sv);
            int cpos = __popcll(gt);
            float upv = __int_as_float(
                __builtin_amdgcn_ds_permute(pa, __float_as_int(lvr)));
            int   upi = __builtin_amdgcn_ds_permute(pa, lir);
            if (lane >= cpos && lane < 20) {
                lvr = (lane == cpos) ? sv : upv;
                lir = (lane == cpos) ? (m0 + j) : upi;
            }
        }
    };

    auto sel4 = [&](int buf, int m0) {
#pragma unroll
        for (int i = 0; i < 4; ++i) {
            int lrow = (w << 2) + i;
            float s = sc[buf][lrow][lane];
            ins(lv[i], li[i], s, m0);
        }
    };

    // chunk-0 list fill: descending bitonic sort of the 64 candidates;
    // ties broken toward lower index (matches strictly-greater insertion).
    auto sortInit = [&](int buf) {
#pragma unroll
        for (int i = 0; i < 4; ++i) {
            int lrow = (w << 2) + i;
            float v = sc[buf][lrow][lane];
            int   id = lane;                 // chunk 0: cand index = lane
#pragma unroll
            for (int k2 = 2; k2 <= 64; k2 <<= 1) {
#pragma unroll
                for (int j = k2 >> 1; j > 0; j >>= 1) {
                    float ov = __shfl_xor(v, j);
                    int   oi = __shfl_xor(id, j);
                    bool keepBig = (((lane & k2) == 0) == ((lane & j) == 0));
                    bool gt = (v > ov) || (v == ov && id < oi);
                    if (gt != keepBig) { v = ov; id = oi; }
                }
            }
            lv[i] = v;                       // lanes 0..19 = top-20 desc
            li[i] = id;                      // lanes >=20 garbage (never read)
        }
    };

    const unsigned short* xcB = xps + (size_t)bc * 8192;
    bf16x8 bh0 = *(const bf16x8*)&xcB[off0];
    bf16x8 bl0 = *(const bf16x8*)&xcB[4096 + off0];
    bf16x8 bh1 = *(const bf16x8*)&xcB[off1];
    bf16x8 bl1 = *(const bf16x8*)&xcB[4096 + off1];
    float xxv = xxb[n_];

    for (int mc = 0; mc < 64; ++mc) {
        f32x4 acc = {0.f, 0.f, 0.f, 0.f};
        acc = __builtin_amdgcn_mfma_f32_16x16x32_bf16(ah[0], bh0, acc, 0, 0, 0);
        acc = __builtin_amdgcn_mfma_f32_16x16x32_bf16(ah[0], bl0, acc, 0, 0, 0);
        acc = __builtin_amdgcn_mfma_f32_16x16x32_bf16(al[0], bh0, acc, 0, 0, 0);
        acc = __builtin_amdgcn_mfma_f32_16x16x32_bf16(al[0], bl0, acc, 0, 0, 0);
        acc = __builtin_amdgcn_mfma_f32_16x16x32_bf16(ah[1], bh1, acc, 0, 0, 0);
        acc = __builtin_amdgcn_mfma_f32_16x16x32_bf16(ah[1], bl1, acc, 0, 0, 0);
        acc = __builtin_amdgcn_mfma_f32_16x16x32_bf16(al[1], bh1, acc, 0, 0, 0);
        acc = __builtin_amdgcn_mfma_f32_16x16x32_bf16(al[1], bl1, acc, 0, 0, 0);

#pragma unroll
        for (int r = 0; r < 4; ++r)
            sc[mc & 3][(wr << 4) + ((lane >> 4) << 2) + r][n_] = 2.f * acc[r] - xxv;

        if (mc + 1 < 64) {
            const unsigned short* xn2 = xps + (size_t)(bc + mc + 1) * 8192;
            bh0 = *(const bf16x8*)&xn2[off0];
            bl0 = *(const bf16x8*)&xn2[4096 + off0];
            bh1 = *(const bf16x8*)&xn2[off1];
            bl1 = *(const bf16x8*)&xn2[4096 + off1];
            xxv = xxb[((mc + 1) << 6) + n_];
        }

        if (mc & 1) {
            if (mc == 3) {
                sortInit(0);                 // chunk 0 (slot 0)
                sel4(1, 1 << 6);             // chunk 1 (slot 1)
            } else if (mc > 3) {
                sel4((mc - 3) & 3, (mc - 3) << 6);
                sel4((mc - 2) & 3, (mc - 2) << 6);
            }
            __syncthreads();
        }
    }

    // tail: chunks 62, 63 (slots 2, 3)
    sel4(2, 62 << 6);
    sel4(3, 63 << 6);

#pragma unroll
    for (int i = 0; i < 4; ++i) {
        int n = n0 + (w << 2) + i;
        if (lane < K_)
            idxg[((size_t)(b * N_ + n)) * K_ + lane] = li[i];
    }
}

// ---------------------------------------------------------------------------
// Kernel C1 (MFMA): gather+BN1 -> split-bf16 images -> MFMA GEMM (proven)
// ---------------------------------------------------------------------------
__global__ void __launch_bounds__(256) k_edge(const float* __restrict__ yA,
                                              const float* __restrict__ dd,
                                              const int* __restrict__ idxg,
                                              const float* __restrict__ wk2,
                                              const float* __restrict__ g1,
                                              const float* __restrict__ bb1,
                                              const float* __restrict__ mm1,
                                              const float* __restrict__ vv1,
                                              const float* __restrict__ g2,
                                              const float* __restrict__ bb2,
                                              const float* __restrict__ mm2,
                                              const float* __restrict__ vv2,
                                              float* __restrict__ ht) {
    __shared__ unsigned short wimg[8192];
    __shared__ float ubuf[64 * 164];
    __shared__ float s1c[64], t1c[64], s2c[64], t2c[64];
    __shared__ float ddl[8][64];
    __shared__ int   il[8][K_];
    __shared__ float hl[8][64];
    unsigned short* timgH = (unsigned short*)ubuf;
    unsigned short* timgL = timgH + 160 * 64;
    float* ct = ubuf;

    int t = threadIdx.x;
    int lane = t & 63;
    int w = t >> 6;
    int blk = blockIdx.x;
    int b = blk >> 9;
    int n0 = (blk & 511) << 3;

    for (int rep = 0; rep < 2; ++rep) {
        int i = rep * 256 + t;
        int row = i >> 3, oct = i & 7;
        float4 wa = *(const float4*)(wk2 + row * 64 + oct * 8);
        float4 wb = *(const float4*)(wk2 + row * 64 + oct * 8 + 4);
        float wv[8] = {wa.x, wa.y, wa.z, wa.w, wb.x, wb.y, wb.z, wb.w};
        bf16x8 hv, lv8;
        split8(wv, hv, lv8);
        int unit = oct ^ (row & 7);
        *(bf16x8*)&wimg[row * 64 + unit * 8] = hv;
        *(bf16x8*)&wimg[4096 + row * 64 + unit * 8] = lv8;
    }
    if (t < 64) {
        float g = g1[t], be = bb1[t], m = mm1[t], v = vv1[t];
        float s = g * rsqrtf(v + EPS_);
        s1c[t] = s; t1c[t] = be - m * s;
        g = g2[t]; be = bb2[t]; m = mm2[t]; v = vv2[t];
        s = g * rsqrtf(v + EPS_);
        s2c[t] = s; t2c[t] = be - m * s;
    }
    size_t pbase = (size_t)(b * N_ + n0);
    for (int i = t; i < 512; i += 256) {
        int pt = i >> 6, o = i & 63;
        ddl[pt][o] = dd[(pbase + pt) * 64 + o];
    }
    if (t < 8 * K_) {
        int pt = t / K_, k = t % K_;
        il[pt][k] = idxg[(pbase + pt) * K_ + k];
    }
    __syncthreads();

    const float* yAb = yA + (size_t)(b * N_) * 64;
    float4 ga[5][2];
    int gcol[5], goct[5], gpt[5];
#pragma unroll
    for (int rep = 0; rep < 5; ++rep) {
        int j = rep * 256 + t;
        int pt = j / 160;
        int r = j - pt * 160;
        int k = r >> 3, oct = r & 7;
        int m = il[pt][k];
        const float* src = yAb + (size_t)m * 64 + oct * 8;
        ga[rep][0] = *(const float4*)src;
        ga[rep][1] = *(const float4*)(src + 4);
        gcol[rep] = pt * 20 + k; goct[rep] = oct; gpt[rep] = pt;
    }
#pragma unroll
    for (int rep = 0; rep < 5; ++rep) {
        int oct = goct[rep], pt = gpt[rep], col = gcol[rep];
        float yv[8] = {ga[rep][0].x, ga[rep][0].y, ga[rep][0].z, ga[rep][0].w,
                       ga[rep][1].x, ga[rep][1].y, ga[rep][1].z, ga[rep][1].w};
        float tv[8];
#pragma unroll
        for (int jj = 0; jj < 8; ++jj) {
            int oc = oct * 8 + jj;
            tv[jj] = lrelu(s1c[oc] * (yv[jj] + ddl[pt][oc]) + t1c[oc]);
        }
        bf16x8 hv, lv8;
        split8(tv, hv, lv8);
        int unit = oct ^ (col & 7);
        *(bf16x8*)&timgH[col * 64 + unit * 8] = hv;
        *(bf16x8*)&timgL[col * 64 + unit * 8] = lv8;
    }
    __syncthreads();

    int anl = (w << 4) + (lane & 15);
    bf16x8 ah[2], al[2];
#pragma unroll
    for (int kc = 0; kc < 2; ++kc) {
        int unit = (kc * 4 + (lane >> 4)) ^ (anl & 7);
        ah[kc] = *(const bf16x8*)&wimg[anl * 64 + unit * 8];
        al[kc] = *(const bf16x8*)&wimg[4096 + anl * 64 + unit * 8];
    }
    f32x4 acc[10];
#pragma unroll
    for (int nt = 0; nt < 10; ++nt) {
        int col = nt * 16 + (lane & 15);
        int u0 = ((lane >> 4)) ^ (col & 7);
        int u1 = (4 + (lane >> 4)) ^ (col & 7);
        bf16x8 bh0 = *(const bf16x8*)&timgH[col * 64 + u0 * 8];
        bf16x8 bl0 = *(const bf16x8*)&timgL[col * 64 + u0 * 8];
        bf16x8 bh1 = *(const bf16x8*)&timgH[col * 64 + u1 * 8];
        bf16x8 bl1 = *(const bf16x8*)&timgL[col * 64 + u1 * 8];
        f32x4 a = {0.f, 0.f, 0.f, 0.f};
        a = __builtin_amdgcn_mfma_f32_16x16x32_bf16(ah[0], bh0, a, 0, 0, 0);
        a = __builtin_amdgcn_mfma_f32_16x16x32_bf16(ah[0], bl0, a, 0, 0, 0);
        a = __builtin_amdgcn_mfma_f32_16x16x32_bf16(al[0], bh0, a, 0, 0, 0);
        a = __builtin_amdgcn_mfma_f32_16x16x32_bf16(al[0], bl0, a, 0, 0, 0);
        a = __builtin_amdgcn_mfma_f32_16x16x32_bf16(ah[1], bh1, a, 0, 0, 0);
        a = __builtin_amdgcn_mfma_f32_16x16x32_bf16(ah[1], bl1, a, 0, 0, 0);
        a = __builtin_amdgcn_mfma_f32_16x16x32_bf16(al[1], bh1, a, 0, 0, 0);
        a = __builtin_amdgcn_mfma_f32_16x16x32_bf16(al[1], bl1, a, 0, 0, 0);
        acc[nt] = a;
    }
    __syncthreads();

#pragma unroll
    for (int nt = 0; nt < 10; ++nt) {
#pragma unroll
        for (int r = 0; r < 4; ++r)
            ct[((w << 4) + ((lane >> 4) << 2) + r) * 164 + nt * 16 + (lane & 15)] =
                acc[nt][r];
    }
    __syncthreads();

#pragma unroll
    for (int rep = 0; rep < 2; ++rep) {
        int pair = rep * 256 + t;
        int o2 = pair >> 3, pt = pair & 7;
        const float* row = &ct[o2 * 164 + pt * 20];
        float4 c0 = *(const float4*)(row + 0);
        float4 c1 = *(const float4*)(row + 4);
        float4 c2 = *(const float4*)(row + 8);
        float4 c3 = *(const float4*)(row + 12);
        float4 c4 = *(const float4*)(row + 16);
        float mx = fmaxf(fmaxf(fmaxf(c0.x, c0.y), fmaxf(c0.z, c0.w)),
                   fmaxf(fmaxf(fmaxf(c1.x, c1.y), fmaxf(c1.z, c1.w)),
                   fmaxf(fmaxf(fmaxf(c2.x, c2.y), fmaxf(c2.z, c2.w)),
                   fmaxf(fmaxf(fmaxf(c3.x, c3.y), fmaxf(c3.z, c3.w)),
                         fmaxf(fmaxf(c4.x, c4.y), fmaxf(c4.z, c4.w))))));
        hl[pt][o2] = lrelu(s2c[o2] * mx + t2c[o2]);
    }
    __syncthreads();

    float* htb = ht + (size_t)b * 64 * N_;
    for (int i = t; i < 512; i += 256) {
        int o = i >> 3, pt2 = i & 7;
        htb[o * N_ + n0 + pt2] = hl[pt2][o];
    }
}

// ---------------------------------------------------------------------------
// Kernel C2 (MFMA): head 64 -> 256 -> 128 -> 1 (proven)
// ---------------------------------------------------------------------------
__global__ void __launch_bounds__(256) k_head(const float* __restrict__ ht,
                                              const float* __restrict__ w1,
                                              const float* __restrict__ g1,
                                              const float* __restrict__ bb1,
                                              const float* __restrict__ mm1,
                                              const float* __restrict__ vv1,
                                              const float* __restrict__ w2,
                                              const float* __restrict__ g2,
                                              const float* __restrict__ bb2,
                                              const float* __restrict__ mm2,
                                              const float* __restrict__ vv2,
                                              const float* __restrict__ w3,
                                              const float* __restrict__ b3,
                                              float* __restrict__ out) {
    __shared__ unsigned int himgH[64 * 36];
    __shared__ unsigned int himgL[64 * 36];
    __shared__ float a1f[64 * 132];
    __shared__ float sA[256], tA[256], sB[128], tB[128], w3s[128];
    __shared__ float outp[4][64];
    int t = threadIdx.x;
    int lane = t & 63;
    int w = t >> 6;
    int blk = blockIdx.x;
    int b = blk >> 6;
    int n0 = (blk & 63) << 6;
    const float* htb = ht + (size_t)b * 64 * N_;

#pragma unroll
    for (int rep = 0; rep < 8; ++rep) {
        int i = rep * 256 + t;
        int pt = i & 63, op = i >> 6;
        float v0 = htb[(2 * op) * N_ + n0 + pt];
        float v1 = htb[(2 * op + 1) * N_ + n0 + pt];
        unsigned short h0 = f2bf(v0), h1 = f2bf(v1);
        unsigned short l0 = f2bf(v0 - bf2f(h0)), l1 = f2bf(v1 - bf2f(h1));
        himgH[pt * 36 + op] = (unsigned int)h0 | ((unsigned int)h1 << 16);
        himgL[pt * 36 + op] = (unsigned int)l0 | ((unsigned int)l1 << 16);
    }
    {
        float g = g1[t], be = bb1[t], m = mm1[t], v = vv1[t];
        float s = g * rsqrtf(v + EPS_);
        sA[t] = s; tA[t] = be - m * s;
    }
    if (t < 128) {
        float g = g2[t], be = bb2[t], m = mm2[t], v = vv2[t];
        float s = g * rsqrtf(v + EPS_);
        sB[t] = s; tB[t] = be - m * s;
        w3s[t] = w3[t];
    }
    __syncthreads();

    f32x4 acc2[2][4];
#pragma unroll
    for (int i = 0; i < 2; ++i)
#pragma unroll
        for (int j = 0; j < 4; ++j) acc2[i][j] = (f32x4){0.f, 0.f, 0.f, 0.f};

    for (int ka = 0; ka < 2; ++ka) {
        bf16x8 wh[2][2], wl[2][2];
#pragma unroll
        for (int mtl2 = 0; mtl2 < 2; ++mtl2) {
            int mabs = 128 * ka + ((2 * w + mtl2) << 4) + (lane & 15);
#pragma unroll
            for (int kc = 0; kc < 2; ++kc) {
                const float* p = w1 + mabs * 64 + kc * 32 + ((lane >> 4) << 3);
                float4 q0 = *(const float4*)p;
                float4 q1 = *(const float4*)(p + 4);
                float vv8[8] = {q0.x, q0.y, q0.z, q0.w, q1.x, q1.y, q1.z, q1.w};
                split8(vv8, wh[mtl2][kc], wl[mtl2][kc]);
            }
        }
#pragma unroll
        for (int nt = 0; nt < 4; ++nt) {
            int pt = (nt << 4) + (lane & 15);
            f32x4 aAcc[2] = {{0.f, 0.f, 0.f, 0.f}, {0.f, 0.f, 0.f, 0.f}};
#pragma unroll
            for (int kc = 0; kc < 2; ++kc) {
                int chb = kc * 32 + ((lane >> 4) << 3);
                bf16x8 bh = *(const bf16x8*)((const unsigned short*)himgH + pt * 72 + chb);
                bf16x8 bl = *(const bf16x8*)((const unsigned short*)himgL + pt * 72 + chb);
#pragma unroll
                for (int mtl2 = 0; mtl2 < 2; ++mtl2) {
                    aAcc[mtl2] = __builtin_amdgcn_mfma_f32_16x16x32_bf16(wh[mtl2][kc], bh, aAcc[mtl2], 0, 0, 0);
                    aAcc[mtl2] = __builtin_amdgcn_mfma_f32_16x16x32_bf16(wh[mtl2][kc], bl, aAcc[mtl2], 0, 0, 0);
                    aAcc[mtl2] = __builtin_amdgcn_mfma_f32_16x16x32_bf16(wl[mtl2][kc], bh, aAcc[mtl2], 0, 0, 0);
                    aAcc[mtl2] = __builtin_amdgcn_mfma_f32_16x16x32_bf16(wl[mtl2][kc], bl, aAcc[mtl2], 0, 0, 0);
                }
            }
#pragma unroll
            for (int mtl2 = 0; mtl2 < 2; ++mtl2) {
                int klocal = ((2 * w + mtl2) << 4) + ((lane >> 4) << 2);
                int rabs = 128 * ka + klocal;
                float4 ov;
                ov.x = lrelu(sA[rabs + 0] * aAcc[mtl2][0] + tA[rabs + 0]);
                ov.y = lrelu(sA[rabs + 1] * aAcc[mtl2][1] + tA[rabs + 1]);
                ov.z = lrelu(sA[rabs + 2] * aAcc[mtl2][2] + tA[rabs + 2]);
                ov.w = lrelu(sA[rabs + 3] * aAcc[mtl2][3] + tA[rabs + 3]);
                *(float4*)&a1f[pt * 132 + klocal] = ov;
            }
        }
        __syncthreads();

#pragma unroll
        for (int kc2 = 0; kc2 < 4; ++kc2) {
            bf16x8 ah2[2], al2[2];
#pragma unroll
            for (int mt2 = 0; mt2 < 2; ++mt2) {
                int oabs = (w << 5) + (mt2 << 4) + (lane & 15);
                const float* p = w2 + oabs * 256 + 128 * ka + kc2 * 32 + ((lane >> 4) << 3);
                float4 q0 = *(const float4*)p;
                float4 q1 = *(const float4*)(p + 4);
                float vv8[8] = {q0.x, q0.y, q0.z, q0.w, q1.x, q1.y, q1.z, q1.w};
                split8(vv8, ah2[mt2], al2[mt2]);
            }
#pragma unroll
            for (int nt = 0; nt < 4; ++nt) {
                int pt = (nt << 4) + (lane & 15);
                int kl = kc2 * 32 + ((lane >> 4) << 3);
                float4 q0 = *(const float4*)&a1f[pt * 132 + kl];
                float4 q1 = *(const float4*)&a1f[pt * 132 + kl + 4];
                float vv8[8] = {q0.x, q0.y, q0.z, q0.w, q1.x, q1.y, q1.z, q1.w};
                bf16x8 bh, bl;
                split8(vv8, bh, bl);
#pragma unroll
                for (int mt2 = 0; mt2 < 2; ++mt2) {
                    acc2[mt2][nt] = __builtin_amdgcn_mfma_f32_16x16x32_bf16(ah2[mt2], bh, acc2[mt2][nt], 0, 0, 0);
                    acc2[mt2][nt] = __builtin_amdgcn_mfma_f32_16x16x32_bf16(ah2[mt2], bl, acc2[mt2][nt], 0, 0, 0);
                    acc2[mt2][nt] = __builtin_amdgcn_mfma_f32_16x16x32_bf16(al2[mt2], bh, acc2[mt2][nt], 0, 0, 0);
                    acc2[mt2][nt] = __builtin_amdgcn_mfma_f32_16x16x32_bf16(al2[mt2], bl, acc2[mt2][nt], 0, 0, 0);
                }
            }
        }
        __syncthreads();
    }

    float part[4] = {0.f, 0.f, 0.f, 0.f};
#pragma unroll
    for (int mt2 = 0; mt2 < 2; ++mt2) {
        int ob = (w << 5) + (mt2 << 4) + ((lane >> 4) << 2);
#pragma unroll
        for (int nt = 0; nt < 4; ++nt) {
#pragma unroll
            for (int r = 0; r < 4; ++r) {
                int o = ob + r;
                float a2v = lrelu(sB[o] * acc2[mt2][nt][r] + tB[o]);
                part[nt] += w3s[o] * a2v;
            }
        }
    }
#pragma unroll
    for (int nt = 0; nt < 4; ++nt) {
        part[nt] += __shfl_xor(part[nt], 16);
        part[nt] += __shfl_xor(part[nt], 32);
    }
    if (lane < 16) {
#pragma unroll
        for (int nt = 0; nt < 4; ++nt)
            outp[w][(nt << 4) + lane] = part[nt];
    }
    __syncthreads();
    if (t < 64)
        out[b * N_ + n0 + t] = outp[0][t] + outp[1][t] + outp[2][t] + outp[3][t] + b3[0];
}

// ---------------------------------------------------------------------------
extern "C" void kernel_launch(void* const* d_in, const int* in_sizes, int n_in,
                              void* d_out, int out_size, void* d_ws, size_t ws_size,
                              hipStream_t stream) {
    (void)in_sizes; (void)n_in; (void)out_size; (void)ws_size;
    const float* x    = (const float*)d_in[0];
    const float* wk1  = (const float*)d_in[1];
    const float* gk1  = (const float*)d_in[2];
    const float* bk1  = (const float*)d_in[3];
    const float* mk1  = (const float*)d_in[4];
    const float* vk1  = (const float*)d_in[5];
    const float* wk2  = (const float*)d_in[6];
    const float* gk2  = (const float*)d_in[7];
    const float* bk2  = (const float*)d_in[8];
    const float* mk2  = (const float*)d_in[9];
    const float* vk2  = (const float*)d_in[10];
    const float* w1   = (const float*)d_in[11];
    const float* g1   = (const float*)d_in[12];
    const float* b1   = (const float*)d_in[13];
    const float* m1   = (const float*)d_in[14];
    const float* v1   = (const float*)d_in[15];
    const float* w2   = (const float*)d_in[16];
    const float* g2   = (const float*)d_in[17];
    const float* b2   = (const float*)d_in[18];
    const float* m2   = (const float*)d_in[19];
    const float* v2   = (const float*)d_in[20];
    const float* w3   = (const float*)d_in[21];
    const float* b3   = (const float*)d_in[22];

    char* ws = (char*)d_ws;
    float* yA  = (float*)(ws);                       //  8 MB
    float* dd  = (float*)(ws + 8388608);             //  8 MB
    float* xx  = (float*)(ws + 16777216);            //  128 KB
    int*   idx = (int*)  (ws + 16908288);            //  2.5 MB
    float* ht  = (float*)(ws + 19529728);            //  8 MB
    unsigned short* xps = (unsigned short*)(ws + 27918336);  // 8 MB split-bf16 images

    k_pre <<<B_ * (N_ / 64), 256, 0, stream>>>(x, wk1, yA, dd, xx, xps);
    k_topk<<<B_ * (N_ / 32), 512, 0, stream>>>(xps, xx, idx);
    k_edge<<<B_ * (N_ / 8),  256, 0, stream>>>(yA, dd, idx, wk2,
                                               gk1, bk1, mk1, vk1,
                                               gk2, bk2, mk2, vk2, ht);
    k_head<<<B_ * (N_ / 64), 256, 0, stream>>>(ht, w1, g1, b1, m1, v1,
                                               w2, g2, b2, m2, v2, w3, b3,
                                               (float*)d_out);
}